// Round 18
// baseline (138.964 us; speedup 1.0000x reference)
//
#include <hip/hip_runtime.h>

typedef _Float16 f16;
typedef __attribute__((ext_vector_type(4))) _Float16 f16x4;
typedef __attribute__((ext_vector_type(8))) _Float16 f16x8;
typedef __attribute__((ext_vector_type(2))) __fp16 fp16x2;
typedef __attribute__((ext_vector_type(4))) float f32x4;
typedef __attribute__((ext_vector_type(16))) float f32x16;
typedef __attribute__((ext_vector_type(2))) unsigned u32x2;

#define MFMA16(a, b, c) __builtin_amdgcn_mfma_f32_16x16x32_f16((a), (b), (c), 0, 0, 0)
#define MFMA32(a, b, c) __builtin_amdgcn_mfma_f32_32x32x16_f16((a), (b), (c), 0, 0, 0)

__device__ __forceinline__ void gload_lds16(const void* g, void* l) {
  __builtin_amdgcn_global_load_lds(
      (const __attribute__((address_space(1))) void*)g,
      (__attribute__((address_space(3))) void*)l, 16, 0, 0);
}

__device__ __forceinline__ unsigned pkrtz(float lo, float hi) {
  union { fp16x2 h; unsigned u; } cv;
  cv.h = __builtin_amdgcn_cvt_pkrtz(lo, hi);
  return cv.u;
}

// exchange halves: a' = [a.lo | b.lo_from_partner], b' = [a.hi_from_partner | b.hi]
__device__ __forceinline__ void xch(unsigned& a, unsigned& b) {
#if __has_builtin(__builtin_amdgcn_permlane32_swap)
  u32x2 r = __builtin_amdgcn_permlane32_swap(a, b, false, false);
  a = r[0];
  b = r[1];
#else
  unsigned sa = __shfl_xor((int)a, 32), sb = __shfl_xor((int)b, 32);
  bool hi = (threadIdx.x & 32) != 0;
  unsigned x = hi ? sb : a;
  unsigned y = hi ? b : sa;
  a = x;
  b = y;
#endif
}

// fragment-layout index helpers (Q/K share one form; V has its own).
// K/Q: lane l of 32-key block kb32, dword-col c  ->  elements
//   [t = kb32*32 + (l&31)][d = c*16 + (l>>5)*8 + e]
__device__ __forceinline__ size_t kq_idx(int t, int d) {
  return (size_t)(((t >> 5) * 4 + (d >> 4)) * 512 +
                  (((t & 31) | (((d >> 3) & 1) << 5)) * 8) + (d & 7));
}
// V: lane l of frag (kb32, db, ks) -> [d = db*32 + (l&31)][t = kb32*32 + ks*16 + (l>>5)*8 + e]
__device__ __forceinline__ size_t v_idx(int t, int d) {
  return (size_t)(((((t >> 5) * 2 + (d >> 5)) * 2 + ((t >> 4) & 1)) * 512) +
                  (((d & 31) | (((t >> 3) & 1) << 5)) * 8) + (t & 7));
}

// ------- fused prep: convert x -> f16, transpose Wqkv & Wproj -> [N][K] f16 -------
__global__ __launch_bounds__(256) void k_prep(
    const float* __restrict__ x, f16* __restrict__ xb,
    const float* __restrict__ Wq, f16* __restrict__ WqT,
    const float* __restrict__ Wp, f16* __restrict__ WpT) {
  __shared__ float tile[64][65];
  int bid = blockIdx.x;
  if (bid < 768) {
    int i = bid * 256 + threadIdx.x;
#pragma unroll
    for (int it = 0; it < 4; ++it, i += 768 * 256) {
      float4 v = ((const float4*)x)[i];
      f16x4 o;
      o[0] = (f16)v.x; o[1] = (f16)v.y; o[2] = (f16)v.z; o[3] = (f16)v.w;
      ((f16x4*)xb)[i] = o;
    }
    return;
  }
  const float* in; f16* out; int N, n0, k0;
  if (bid < 1200) {
    int t = bid - 768;
    in = Wq; out = WqT; N = 2304;
    n0 = (t % 36) * 64; k0 = (t / 36) * 64;
  } else {
    int t = bid - 1200;
    in = Wp; out = WpT; N = 768;
    n0 = (t % 12) * 64; k0 = (t / 12) * 64;
  }
  int c = threadIdx.x & 63, r4 = threadIdx.x >> 6;
#pragma unroll
  for (int i = 0; i < 16; ++i) {
    int r = i * 4 + r4;
    tile[r][c] = in[(size_t)(k0 + r) * N + n0 + c];
  }
  __syncthreads();
#pragma unroll
  for (int i = 0; i < 16; ++i) {
    int r = i * 4 + r4;
    out[(size_t)(n0 + r) * 768 + k0 + c] = (f16)tile[c][r];
  }
}

// --------- 128x128 f16 MFMA GEMM, BK=64, XOR-swizzled LDS, 2-phase dbuf ---------
// T1: bijective XCD-chunked block swizzle (nwg%8==0 for both grids) so the 32
// consecutive blocks sharing a B-panel land on one XCD's L2, not all eight.
// LDS logical layout [128 rows][8 chunks of 16B]; physical chunk = c ^ (row&7);
// swizzle applied on the GLOBAL source at stage time + ds_read addr (m201).
// Pipeline (T3-minimal): stage(buf^1, t+1) issued BEFORE compute(buf[t]).
// mode 0: scatter to FRAGMENT-layout Qf/Kf/Vf; mode 1: out = acc + bias (fp32)
__global__ __launch_bounds__(256) void k_gemm(
    const f16* __restrict__ A, const f16* __restrict__ BT,
    int M, int N, int K, int mode,
    f16* __restrict__ Qo, f16* __restrict__ Ko, f16* __restrict__ Vt,
    const float* __restrict__ bias, float* __restrict__ out) {
  __shared__ f16 As[2][128 * 64];
  __shared__ f16 Bs[2][128 * 64];
  int tid = threadIdx.x;
  int wv = tid >> 6;
  int lane = tid & 63;
  int lr = lane & 15, lc = lane >> 4;
  // T1 XCD swizzle: orig id -> chunked id (bijective; nwg multiple of 8)
  int nwg = gridDim.x * gridDim.y;
  int id = blockIdx.y * gridDim.x + blockIdx.x;
  int q8 = nwg >> 3;
  int nid = (id & 7) * q8 + (id >> 3);
  int bx = nid % gridDim.x, by = nid / gridDim.x;
  int m0 = bx * 128, n0 = by * 128;
  int wm = (wv >> 1) * 64, wn = (wv & 1) * 64;
  f32x4 acc[4][4] = {};
  int nK = K >> 6;  // BK = 64

  // stage one 128x64 tile pair into buffer bf (8 gload_lds16 issues/thread)
  auto stage = [&](int bf, int k0) {
#pragma unroll
    for (int i = 0; i < 4; ++i) {
      int g = i * 256 + tid;
      int row = g >> 3;
      int ch = (g & 7) ^ (row & 7);
      gload_lds16(A + (size_t)(m0 + row) * K + k0 + ch * 8,
                  As[bf] + (size_t)(i * 256 + (tid & 192)) * 8);
    }
#pragma unroll
    for (int i = 0; i < 4; ++i) {
      int g = i * 256 + tid;
      int row = g >> 3;
      int ch = (g & 7) ^ (row & 7);
      gload_lds16(BT + (size_t)(n0 + row) * K + k0 + ch * 8,
                  Bs[bf] + (size_t)(i * 256 + (tid & 192)) * 8);
    }
  };

  stage(0, 0);
  __syncthreads();  // drain prologue stage
  int cur = 0;
  for (int kt = 0; kt < nK; ++kt) {
    // issue next tile's loads first — latency hides under this tile's compute
    if (kt + 1 < nK) stage(cur ^ 1, (kt + 1) << 6);
    // two K=32 sub-steps; fragment read chunk = ((kh<<2)|lc) ^ (lr&7)
#pragma unroll
    for (int kh = 0; kh < 2; ++kh) {
      f16x8 af[4], bf[4];
      int csw = (((kh << 2) | lc) ^ (lr & 7)) << 3;
#pragma unroll
      for (int mi = 0; mi < 4; ++mi)
        af[mi] = *(const f16x8*)&As[cur][(wm + mi * 16 + lr) * 64 + csw];
#pragma unroll
      for (int ni = 0; ni < 4; ++ni)
        bf[ni] = *(const f16x8*)&Bs[cur][(wn + ni * 16 + lr) * 64 + csw];
#pragma unroll
      for (int mi = 0; mi < 4; ++mi)
#pragma unroll
        for (int ni = 0; ni < 4; ++ni)
          acc[mi][ni] = MFMA16(af[mi], bf[ni], acc[mi][ni]);
    }
    __syncthreads();  // drains prefetch (post-compute) + protects buf reuse
    cur ^= 1;
  }
  if (mode == 0) {
#pragma unroll
    for (int ni = 0; ni < 4; ++ni) {
      int col = n0 + wn + ni * 16 + lr;
      int s = col / 768;
      int hh = (col - s * 768) >> 6;
      int d = col & 63;
      if (s == 2) {
#pragma unroll
        for (int mi = 0; mi < 4; ++mi) {
          int row0 = m0 + wm + mi * 16 + lc * 4;
          int b = row0 >> 11, t = row0 & 2047;
          f16x4 tv;
#pragma unroll
          for (int r = 0; r < 4; ++r) tv[r] = (f16)acc[mi][ni][r];
          // 4 consecutive t = 4 consecutive e within one fragment octet
          *(f16x4*)&Vt[((size_t)(b * 12 + hh) << 17) | v_idx(t, d)] = tv;
        }
      } else {
        f16* dst = (s == 0) ? Qo : Ko;
#pragma unroll
        for (int mi = 0; mi < 4; ++mi)
#pragma unroll
          for (int r = 0; r < 4; ++r) {
            int row = m0 + wm + mi * 16 + lc * 4 + r;
            int b = row >> 11, t = row & 2047;
            dst[((size_t)(b * 12 + hh) << 17) | kq_idx(t, d)] =
                (f16)acc[mi][ni][r];
          }
      }
    }
  } else {
#pragma unroll
    for (int ni = 0; ni < 4; ++ni) {
      int col = n0 + wn + ni * 16 + lr;
      float bv = bias[col];
#pragma unroll
      for (int mi = 0; mi < 4; ++mi)
#pragma unroll
        for (int r = 0; r < 4; ++r) {
          int row = m0 + wm + mi * 16 + lc * 4 + r;
          out[(size_t)row * 768 + col] = acc[mi][ni][r] + bv;
        }
    }
  }
}

// ---- causal softplus-normalized attention: 4-wave split-K, P in registers ----
// Block (bh, qt), 256 threads. Wave wv handles 64-key tiles kt = wv, wv+4, ...
// Q/K/V live in FRAGMENT-layout buffers -> every load is base + lane*16B,
// fully coalesced (1 KB/instr, 8 cache lines instead of 32 — the r13 fix).
// Swapped 32x32 MFMA body: S = mfma32(A=K, B=Q); softplus+rowsum in-lane;
// P->f16 via cvt_pkrtz + permlane32_swap; O^T += mfma32(A=V-frag, B=P).
// K prefetched right after QK^T; all 8 V frags issued up-front (MLP).
// LDS untouched in the k-loop; single combine at the end (comb[4][32][68]).
// launch_bounds (256,4): body measured 84 VGPR (r13) < 128 budget -> 4 waves/SIMD.
__global__ __launch_bounds__(256, 4) void k_attn(const f16* __restrict__ Q,
                                                 const f16* __restrict__ K,
                                                 const f16* __restrict__ Vt,
                                                 f16* __restrict__ Ab) {
  __shared__ __align__(16) char smem[35328];
  float (*comb)[32][68] = (float(*)[32][68])smem;  // [wv][q][d]
  float* rscomb = (float*)(smem + 34816);          // [wv][q]
  int tid = threadIdx.x, wv = tid >> 6, lane = tid & 63;
  int ql = lane & 31;
  int hi = lane >> 5;
  int hi4 = hi << 2;
  int bh = blockIdx.x;
  int qt = 63 - (int)blockIdx.y;  // heavy blocks dispatch first
  int qw = qt * 32;
  int b = bh / 12, h = bh - b * 12;
  const f16* Qp = Q + ((size_t)bh << 17);
  const f16* Kp = K + ((size_t)bh << 17);
  const f16* Vp = Vt + ((size_t)bh << 17);
  int l8 = lane * 8;

  const f16 a16 = (f16)0.18033688f;  // 0.125 * log2(e): fold scale into Q
  f16x8 qf[4];
#pragma unroll
  for (int c = 0; c < 4; ++c) {
    qf[c] = *(const f16x8*)&Qp[((qw >> 5) * 4 + c) * 512 + l8];
    qf[c] *= a16;
  }

  f32x16 o0 = {}, o1 = {};  // O^T[d = db*32 + crow(r,hi)][q] partials
  float rsp[4] = {0.f, 0.f, 0.f, 0.f};
  f16x8 kf[2][4];

  auto loadK = [&](int kb) {
#pragma unroll
    for (int kblk = 0; kblk < 2; ++kblk)
#pragma unroll
      for (int c = 0; c < 4; ++c)
        kf[kblk][c] =
            *(const f16x8*)&Kp[(((kb >> 5) + kblk) * 4 + c) * 512 + l8];
  };
  auto vfrag = [&](int kb32, int db, int ks) {
    return *(const f16x8*)&Vp[((kb32 * 2 + db) * 2 + ks) * 512 + l8];
  };

  // softplus: w' = log2(1+2^z) (uniform ln2 cancels in w/rowsum), in-place.
  auto spblk = [&](f32x16& sv, bool domask) {
#pragma unroll
    for (int r = 0; r < 16; ++r) {
      float z = sv[r];
      float w = __builtin_amdgcn_logf(1.f + __builtin_amdgcn_exp2f(z));
      if (domask) {
        int kl = (r & 3) + ((r >> 2) << 3) + hi4;
        w = (kl <= ql) ? w : 0.f;
      }
      rsp[r & 3] += w;
      sv[r] = w;
    }
  };

  // pack P to f16, exchange halves, feed PV for one 32-key block
  auto pvblk = [&](f32x16& sv, f16x8& vfa, f16x8& vfa2, f16x8& vfb,
                   f16x8& vfb2) {
#pragma unroll
    for (int ks = 0; ks < 2; ++ks) {
      unsigned Aw = pkrtz(sv[ks * 8 + 0], sv[ks * 8 + 1]);
      unsigned Bw = pkrtz(sv[ks * 8 + 2], sv[ks * 8 + 3]);
      unsigned Cw = pkrtz(sv[ks * 8 + 4], sv[ks * 8 + 5]);
      unsigned Dw = pkrtz(sv[ks * 8 + 6], sv[ks * 8 + 7]);
      xch(Aw, Cw);
      xch(Bw, Dw);
      union { unsigned u[4]; f16x8 v; } pf;
      pf.u[0] = Aw; pf.u[1] = Bw; pf.u[2] = Cw; pf.u[3] = Dw;
      o0 = MFMA32(ks ? vfa2 : vfa, pf.v, o0);
      o1 = MFMA32(ks ? vfb2 : vfb, pf.v, o1);
    }
  };

  auto tile = [&](int kb, bool dob1, bool mask, int kbn) {
    // 1. QK^T on prefetched kf (kf dead after this)
    f32x16 s0 = {}, s1 = {};
#pragma unroll
    for (int c = 0; c < 4; ++c) s0 = MFMA32(kf[0][c], qf[c], s0);
    if (dob1) {
#pragma unroll
      for (int c = 0; c < 4; ++c) s1 = MFMA32(kf[1][c], qf[c], s1);
    }
    // 2. prefetch this wave's next K immediately (longest latency to hide)
    if (kbn >= 0) loadK(kbn);
    // 3. all 8 V fragments issued up-front (coalesced; MLP)
    int kb32 = kb >> 5;
    f16x8 va0 = vfrag(kb32, 0, 0), va1 = vfrag(kb32, 0, 1);
    f16x8 vb0 = vfrag(kb32, 1, 0), vb1 = vfrag(kb32, 1, 1);
    f16x8 wa0, wa1, wb0, wb1;
    if (dob1) {
      wa0 = vfrag(kb32 + 1, 0, 0); wa1 = vfrag(kb32 + 1, 0, 1);
      wb0 = vfrag(kb32 + 1, 1, 0); wb1 = vfrag(kb32 + 1, 1, 1);
    }
    // 4. softplus + pack + PV per 32-key block
    spblk(s0, mask && !dob1);
    pvblk(s0, va0, va1, vb0, vb1);
    if (dob1) {
      spblk(s1, mask);
      pvblk(s1, wa0, wa1, wb0, wb1);
    }
  };

  int dt = qt >> 1;     // diagonal 64-tile index
  bool odd = (qt & 1);  // odd: kblk0 full, kblk1 diag; even: kblk0 diag only
  int nfull = (dt > wv) ? ((dt - wv + 3) >> 2) : 0;  // full tiles for this wave
  bool owndiag = ((dt & 3) == wv);
  if (nfull > 0 || owndiag) loadK(nfull > 0 ? wv * 64 : dt * 64);
  for (int i = 0; i < nfull; ++i) {
    int kb = (wv + 4 * i) * 64;
    int kbn = (i + 1 < nfull) ? kb + 256 : (owndiag ? dt * 64 : -1);
    tile(kb, true, false, kbn);
  }
  if (owndiag) tile(dt * 64, odd, true, -1);

  // per-wave rowsum for q=ql (combine the two key-halves)
  float rs = (rsp[0] + rsp[1]) + (rsp[2] + rsp[3]);
  rs += __shfl_xor(rs, 32);

  // deposit per-wave partials (LDS first touched here; no prior barrier needed)
  if (hi == 0) rscomb[wv * 32 + ql] = rs;
#pragma unroll
  for (int db = 0; db < 2; ++db) {
    const f32x16& oo = db ? o1 : o0;
#pragma unroll
    for (int r = 0; r < 16; ++r) {
      int d = db * 32 + (r & 3) + ((r >> 2) << 3) + hi4;
      comb[wv][ql][d] = oo[r];
    }
  }
  __syncthreads();

  // cross-wave combine: thread -> (row, 8 d's); normalize; store f16
  int row = tid >> 3, d0 = (tid & 7) << 3;
  float inv = 1.0f / (rscomb[row] + rscomb[32 + row] + rscomb[64 + row] +
                      rscomb[96 + row]);
  float sum[8] = {};
#pragma unroll
  for (int w = 0; w < 4; ++w) {
    float4 a = *(const float4*)&comb[w][row][d0];
    float4 c = *(const float4*)&comb[w][row][d0 + 4];
    sum[0] += a.x; sum[1] += a.y; sum[2] += a.z; sum[3] += a.w;
    sum[4] += c.x; sum[5] += c.y; sum[6] += c.z; sum[7] += c.w;
  }
  f16x8 o8;
#pragma unroll
  for (int e = 0; e < 8; ++e) o8[e] = (f16)(sum[e] * inv);
  *(f16x8*)&Ab[((size_t)b * 2048 + qw + row) * 768 + h * 64 + d0] = o8;
}

// ---------------- host ----------------
extern "C" void kernel_launch(void* const* d_in, const int* in_sizes, int n_in,
                              void* d_out, int out_size, void* d_ws,
                              size_t ws_size, hipStream_t stream) {
  const float* x = (const float*)d_in[0];
  const float* Wqkv = (const float*)d_in[1];
  const float* Wproj = (const float*)d_in[2];
  const float* bproj = (const float*)d_in[3];
  float* out = (float*)d_out;
  char* ws = (char*)d_ws;

  f16* xb     = (f16*)(ws + 0);         // 4096x768
  f16* WqkvT  = (f16*)(ws + 6291456);   // 2304x768
  f16* WprojT = (f16*)(ws + 9830400);   // 768x768
  f16* Qb     = (f16*)(ws + 11010048);  // 24x131072 (fragment layout)
  f16* Kb     = (f16*)(ws + 17301504);  // 24x131072 (fragment layout)
  f16* Vtb    = (f16*)(ws + 23592960);  // 24x131072 (fragment layout)
  f16* Ab     = (f16*)(ws + 29884416);  // 4096x768
  // total 36,175,872 B

  k_prep<<<1344, 256, 0, stream>>>(x, xb, Wqkv, WqkvT, Wproj, WprojT);
  k_gemm<<<dim3(32, 18), 256, 0, stream>>>(xb, WqkvT, 4096, 2304, 768, 0, Qb,
                                           Kb, Vtb, nullptr, nullptr);
  k_attn<<<dim3(24, 64), 256, 0, stream>>>(Qb, Kb, Vtb, Ab);
  k_gemm<<<dim3(32, 6), 256, 0, stream>>>(Ab, WprojT, 4096, 768, 768, 1,
                                          nullptr, nullptr, nullptr, bproj, out);
}

// Round 19
// 87.613 us; speedup vs baseline: 1.5861x; 1.5861x over previous
//
#include <hip/hip_runtime.h>

typedef _Float16 f16;
typedef __attribute__((ext_vector_type(4))) _Float16 f16x4;
typedef __attribute__((ext_vector_type(8))) _Float16 f16x8;
typedef __attribute__((ext_vector_type(2))) __fp16 fp16x2;
typedef __attribute__((ext_vector_type(4))) float f32x4;
typedef __attribute__((ext_vector_type(16))) float f32x16;
typedef __attribute__((ext_vector_type(2))) unsigned u32x2;

#define MFMA16(a, b, c) __builtin_amdgcn_mfma_f32_16x16x32_f16((a), (b), (c), 0, 0, 0)
#define MFMA32(a, b, c) __builtin_amdgcn_mfma_f32_32x32x16_f16((a), (b), (c), 0, 0, 0)

__device__ __forceinline__ void gload_lds16(const void* g, void* l) {
  __builtin_amdgcn_global_load_lds(
      (const __attribute__((address_space(1))) void*)g,
      (__attribute__((address_space(3))) void*)l, 16, 0, 0);
}

__device__ __forceinline__ unsigned pkrtz(float lo, float hi) {
  union { fp16x2 h; unsigned u; } cv;
  cv.h = __builtin_amdgcn_cvt_pkrtz(lo, hi);
  return cv.u;
}

// exchange halves: a' = [a.lo | b.lo_from_partner], b' = [a.hi_from_partner | b.hi]
__device__ __forceinline__ void xch(unsigned& a, unsigned& b) {
#if __has_builtin(__builtin_amdgcn_permlane32_swap)
  u32x2 r = __builtin_amdgcn_permlane32_swap(a, b, false, false);
  a = r[0];
  b = r[1];
#else
  unsigned sa = __shfl_xor((int)a, 32), sb = __shfl_xor((int)b, 32);
  bool hi = (threadIdx.x & 32) != 0;
  unsigned x = hi ? sb : a;
  unsigned y = hi ? b : sa;
  a = x;
  b = y;
#endif
}

// fragment-layout index helpers (Q/K share one form; V has its own).
// K/Q: lane l of 32-key block kb32, dword-col c  ->  elements
//   [t = kb32*32 + (l&31)][d = c*16 + (l>>5)*8 + e]
__device__ __forceinline__ size_t kq_idx(int t, int d) {
  return (size_t)(((t >> 5) * 4 + (d >> 4)) * 512 +
                  (((t & 31) | (((d >> 3) & 1) << 5)) * 8) + (d & 7));
}
// V: lane l of frag (kb32, db, ks) -> [d = db*32 + (l&31)][t = kb32*32 + ks*16 + (l>>5)*8 + e]
__device__ __forceinline__ size_t v_idx(int t, int d) {
  return (size_t)(((((t >> 5) * 2 + (d >> 5)) * 2 + ((t >> 4) & 1)) * 512) +
                  (((d & 31) | (((t >> 3) & 1) << 5)) * 8) + (t & 7));
}

// ------- fused prep: convert x -> f16, transpose Wqkv & Wproj -> [N][K] f16 -------
__global__ __launch_bounds__(256) void k_prep(
    const float* __restrict__ x, f16* __restrict__ xb,
    const float* __restrict__ Wq, f16* __restrict__ WqT,
    const float* __restrict__ Wp, f16* __restrict__ WpT) {
  __shared__ float tile[64][65];
  int bid = blockIdx.x;
  if (bid < 768) {
    int i = bid * 256 + threadIdx.x;
#pragma unroll
    for (int it = 0; it < 4; ++it, i += 768 * 256) {
      float4 v = ((const float4*)x)[i];
      f16x4 o;
      o[0] = (f16)v.x; o[1] = (f16)v.y; o[2] = (f16)v.z; o[3] = (f16)v.w;
      ((f16x4*)xb)[i] = o;
    }
    return;
  }
  const float* in; f16* out; int N, n0, k0;
  if (bid < 1200) {
    int t = bid - 768;
    in = Wq; out = WqT; N = 2304;
    n0 = (t % 36) * 64; k0 = (t / 36) * 64;
  } else {
    int t = bid - 1200;
    in = Wp; out = WpT; N = 768;
    n0 = (t % 12) * 64; k0 = (t / 12) * 64;
  }
  int c = threadIdx.x & 63, r4 = threadIdx.x >> 6;
#pragma unroll
  for (int i = 0; i < 16; ++i) {
    int r = i * 4 + r4;
    tile[r][c] = in[(size_t)(k0 + r) * N + n0 + c];
  }
  __syncthreads();
#pragma unroll
  for (int i = 0; i < 16; ++i) {
    int r = i * 4 + r4;
    out[(size_t)(n0 + r) * 768 + k0 + c] = (f16)tile[c][r];
  }
}

// --------- 128x128 f16 MFMA GEMM, BK=64, XOR-swizzled LDS, 2-phase dbuf ---------
// T1: bijective XCD-chunked block swizzle (nwg%8==0 for both grids) so the 32
// consecutive blocks sharing a B-panel land on one XCD's L2, not all eight.
// LDS logical layout [128 rows][8 chunks of 16B]; physical chunk = c ^ (row&7);
// swizzle applied on the GLOBAL source at stage time + ds_read addr (m201).
// Pipeline (T3-minimal): stage(buf^1, t+1) issued BEFORE compute(buf[t]).
// mode 0: scatter to FRAGMENT-layout Qf/Kf/Vf; mode 1: out = acc + bias (fp32)
__global__ __launch_bounds__(256) void k_gemm(
    const f16* __restrict__ A, const f16* __restrict__ BT,
    int M, int N, int K, int mode,
    f16* __restrict__ Qo, f16* __restrict__ Ko, f16* __restrict__ Vt,
    const float* __restrict__ bias, float* __restrict__ out) {
  __shared__ f16 As[2][128 * 64];
  __shared__ f16 Bs[2][128 * 64];
  int tid = threadIdx.x;
  int wv = tid >> 6;
  int lane = tid & 63;
  int lr = lane & 15, lc = lane >> 4;
  // T1 XCD swizzle: orig id -> chunked id (bijective; nwg multiple of 8)
  int nwg = gridDim.x * gridDim.y;
  int id = blockIdx.y * gridDim.x + blockIdx.x;
  int q8 = nwg >> 3;
  int nid = (id & 7) * q8 + (id >> 3);
  int bx = nid % gridDim.x, by = nid / gridDim.x;
  int m0 = bx * 128, n0 = by * 128;
  int wm = (wv >> 1) * 64, wn = (wv & 1) * 64;
  f32x4 acc[4][4] = {};
  int nK = K >> 6;  // BK = 64

  // stage one 128x64 tile pair into buffer bf (8 gload_lds16 issues/thread)
  auto stage = [&](int bf, int k0) {
#pragma unroll
    for (int i = 0; i < 4; ++i) {
      int g = i * 256 + tid;
      int row = g >> 3;
      int ch = (g & 7) ^ (row & 7);
      gload_lds16(A + (size_t)(m0 + row) * K + k0 + ch * 8,
                  As[bf] + (size_t)(i * 256 + (tid & 192)) * 8);
    }
#pragma unroll
    for (int i = 0; i < 4; ++i) {
      int g = i * 256 + tid;
      int row = g >> 3;
      int ch = (g & 7) ^ (row & 7);
      gload_lds16(BT + (size_t)(n0 + row) * K + k0 + ch * 8,
                  Bs[bf] + (size_t)(i * 256 + (tid & 192)) * 8);
    }
  };

  stage(0, 0);
  __syncthreads();  // drain prologue stage
  int cur = 0;
  for (int kt = 0; kt < nK; ++kt) {
    // issue next tile's loads first — latency hides under this tile's compute
    if (kt + 1 < nK) stage(cur ^ 1, (kt + 1) << 6);
    // two K=32 sub-steps; fragment read chunk = ((kh<<2)|lc) ^ (lr&7)
#pragma unroll
    for (int kh = 0; kh < 2; ++kh) {
      f16x8 af[4], bf[4];
      int csw = (((kh << 2) | lc) ^ (lr & 7)) << 3;
#pragma unroll
      for (int mi = 0; mi < 4; ++mi)
        af[mi] = *(const f16x8*)&As[cur][(wm + mi * 16 + lr) * 64 + csw];
#pragma unroll
      for (int ni = 0; ni < 4; ++ni)
        bf[ni] = *(const f16x8*)&Bs[cur][(wn + ni * 16 + lr) * 64 + csw];
#pragma unroll
      for (int mi = 0; mi < 4; ++mi)
#pragma unroll
        for (int ni = 0; ni < 4; ++ni)
          acc[mi][ni] = MFMA16(af[mi], bf[ni], acc[mi][ni]);
    }
    __syncthreads();  // drains prefetch (post-compute) + protects buf reuse
    cur ^= 1;
  }
  if (mode == 0) {
#pragma unroll
    for (int ni = 0; ni < 4; ++ni) {
      int col = n0 + wn + ni * 16 + lr;
      int s = col / 768;
      int hh = (col - s * 768) >> 6;
      int d = col & 63;
      if (s == 2) {
#pragma unroll
        for (int mi = 0; mi < 4; ++mi) {
          int row0 = m0 + wm + mi * 16 + lc * 4;
          int b = row0 >> 11, t = row0 & 2047;
          f16x4 tv;
#pragma unroll
          for (int r = 0; r < 4; ++r) tv[r] = (f16)acc[mi][ni][r];
          // 4 consecutive t = 4 consecutive e within one fragment octet
          *(f16x4*)&Vt[((size_t)(b * 12 + hh) << 17) | v_idx(t, d)] = tv;
        }
      } else {
        f16* dst = (s == 0) ? Qo : Ko;
#pragma unroll
        for (int mi = 0; mi < 4; ++mi)
#pragma unroll
          for (int r = 0; r < 4; ++r) {
            int row = m0 + wm + mi * 16 + lc * 4 + r;
            int b = row >> 11, t = row & 2047;
            dst[((size_t)(b * 12 + hh) << 17) | kq_idx(t, d)] =
                (f16)acc[mi][ni][r];
          }
      }
    }
  } else {
#pragma unroll
    for (int ni = 0; ni < 4; ++ni) {
      int col = n0 + wn + ni * 16 + lr;
      float bv = bias[col];
#pragma unroll
      for (int mi = 0; mi < 4; ++mi)
#pragma unroll
        for (int r = 0; r < 4; ++r) {
          int row = m0 + wm + mi * 16 + lc * 4 + r;
          out[(size_t)row * 768 + col] = acc[mi][ni][r] + bv;
        }
    }
  }
}

// ---- causal softplus-normalized attention: 4-wave split-K, P in registers ----
// Block (bh, qt), 256 threads. Wave wv handles 64-key tiles kt = wv, wv+4, ...
// Q/K/V live in FRAGMENT-layout buffers -> every load is base + lane*16B,
// fully coalesced (1 KB/instr, 8 cache lines instead of 32 — the r13 fix).
// Swapped 32x32 MFMA body: S = mfma32(A=K, B=Q); softplus+rowsum in-lane;
// P->f16 via cvt_pkrtz + permlane32_swap; O^T += mfma32(A=V-frag, B=P).
// K prefetched right after QK^T; all 8 V frags issued up-front (MLP).
// LDS untouched in the k-loop; single combine at the end (comb[4][32][68]).
// launch_bounds (256,3): bound 4 forces 64 arch-VGPRs -> catastrophic spills
// (r12, r18: FETCH 95-120MB, +50us). This body NEEDS ~110 regs; 3 is the max.
__global__ __launch_bounds__(256, 3) void k_attn(const f16* __restrict__ Q,
                                                 const f16* __restrict__ K,
                                                 const f16* __restrict__ Vt,
                                                 f16* __restrict__ Ab) {
  __shared__ __align__(16) char smem[35328];
  float (*comb)[32][68] = (float(*)[32][68])smem;  // [wv][q][d]
  float* rscomb = (float*)(smem + 34816);          // [wv][q]
  int tid = threadIdx.x, wv = tid >> 6, lane = tid & 63;
  int ql = lane & 31;
  int hi = lane >> 5;
  int hi4 = hi << 2;
  int bh = blockIdx.x;
  int qt = 63 - (int)blockIdx.y;  // heavy blocks dispatch first
  int qw = qt * 32;
  int b = bh / 12, h = bh - b * 12;
  const f16* Qp = Q + ((size_t)bh << 17);
  const f16* Kp = K + ((size_t)bh << 17);
  const f16* Vp = Vt + ((size_t)bh << 17);
  int l8 = lane * 8;

  const f16 a16 = (f16)0.18033688f;  // 0.125 * log2(e): fold scale into Q
  f16x8 qf[4];
#pragma unroll
  for (int c = 0; c < 4; ++c) {
    qf[c] = *(const f16x8*)&Qp[((qw >> 5) * 4 + c) * 512 + l8];
    qf[c] *= a16;
  }

  f32x16 o0 = {}, o1 = {};  // O^T[d = db*32 + crow(r,hi)][q] partials
  float rsp[4] = {0.f, 0.f, 0.f, 0.f};
  f16x8 kf[2][4];

  auto loadK = [&](int kb) {
#pragma unroll
    for (int kblk = 0; kblk < 2; ++kblk)
#pragma unroll
      for (int c = 0; c < 4; ++c)
        kf[kblk][c] =
            *(const f16x8*)&Kp[(((kb >> 5) + kblk) * 4 + c) * 512 + l8];
  };
  auto vfrag = [&](int kb32, int db, int ks) {
    return *(const f16x8*)&Vp[((kb32 * 2 + db) * 2 + ks) * 512 + l8];
  };

  // softplus: w' = log2(1+2^z) (uniform ln2 cancels in w/rowsum), in-place.
  auto spblk = [&](f32x16& sv, bool domask) {
#pragma unroll
    for (int r = 0; r < 16; ++r) {
      float z = sv[r];
      float w = __builtin_amdgcn_logf(1.f + __builtin_amdgcn_exp2f(z));
      if (domask) {
        int kl = (r & 3) + ((r >> 2) << 3) + hi4;
        w = (kl <= ql) ? w : 0.f;
      }
      rsp[r & 3] += w;
      sv[r] = w;
    }
  };

  // pack P to f16, exchange halves, feed PV for one 32-key block
  auto pvblk = [&](f32x16& sv, f16x8& vfa, f16x8& vfa2, f16x8& vfb,
                   f16x8& vfb2) {
#pragma unroll
    for (int ks = 0; ks < 2; ++ks) {
      unsigned Aw = pkrtz(sv[ks * 8 + 0], sv[ks * 8 + 1]);
      unsigned Bw = pkrtz(sv[ks * 8 + 2], sv[ks * 8 + 3]);
      unsigned Cw = pkrtz(sv[ks * 8 + 4], sv[ks * 8 + 5]);
      unsigned Dw = pkrtz(sv[ks * 8 + 6], sv[ks * 8 + 7]);
      xch(Aw, Cw);
      xch(Bw, Dw);
      union { unsigned u[4]; f16x8 v; } pf;
      pf.u[0] = Aw; pf.u[1] = Bw; pf.u[2] = Cw; pf.u[3] = Dw;
      o0 = MFMA32(ks ? vfa2 : vfa, pf.v, o0);
      o1 = MFMA32(ks ? vfb2 : vfb, pf.v, o1);
    }
  };

  auto tile = [&](int kb, bool dob1, bool mask, int kbn) {
    // 1. QK^T on prefetched kf (kf dead after this)
    f32x16 s0 = {}, s1 = {};
#pragma unroll
    for (int c = 0; c < 4; ++c) s0 = MFMA32(kf[0][c], qf[c], s0);
    if (dob1) {
#pragma unroll
      for (int c = 0; c < 4; ++c) s1 = MFMA32(kf[1][c], qf[c], s1);
    }
    // 2. prefetch this wave's next K immediately (longest latency to hide)
    if (kbn >= 0) loadK(kbn);
    // 3. all 8 V fragments issued up-front (coalesced; MLP)
    int kb32 = kb >> 5;
    f16x8 va0 = vfrag(kb32, 0, 0), va1 = vfrag(kb32, 0, 1);
    f16x8 vb0 = vfrag(kb32, 1, 0), vb1 = vfrag(kb32, 1, 1);
    f16x8 wa0, wa1, wb0, wb1;
    if (dob1) {
      wa0 = vfrag(kb32 + 1, 0, 0); wa1 = vfrag(kb32 + 1, 0, 1);
      wb0 = vfrag(kb32 + 1, 1, 0); wb1 = vfrag(kb32 + 1, 1, 1);
    }
    // 4. softplus + pack + PV per 32-key block
    spblk(s0, mask && !dob1);
    pvblk(s0, va0, va1, vb0, vb1);
    if (dob1) {
      spblk(s1, mask);
      pvblk(s1, wa0, wa1, wb0, wb1);
    }
  };

  int dt = qt >> 1;     // diagonal 64-tile index
  bool odd = (qt & 1);  // odd: kblk0 full, kblk1 diag; even: kblk0 diag only
  int nfull = (dt > wv) ? ((dt - wv + 3) >> 2) : 0;  // full tiles for this wave
  bool owndiag = ((dt & 3) == wv);
  if (nfull > 0 || owndiag) loadK(nfull > 0 ? wv * 64 : dt * 64);
  for (int i = 0; i < nfull; ++i) {
    int kb = (wv + 4 * i) * 64;
    int kbn = (i + 1 < nfull) ? kb + 256 : (owndiag ? dt * 64 : -1);
    tile(kb, true, false, kbn);
  }
  if (owndiag) tile(dt * 64, odd, true, -1);

  // per-wave rowsum for q=ql (combine the two key-halves)
  float rs = (rsp[0] + rsp[1]) + (rsp[2] + rsp[3]);
  rs += __shfl_xor(rs, 32);

  // deposit per-wave partials (LDS first touched here; no prior barrier needed)
  if (hi == 0) rscomb[wv * 32 + ql] = rs;
#pragma unroll
  for (int db = 0; db < 2; ++db) {
    const f32x16& oo = db ? o1 : o0;
#pragma unroll
    for (int r = 0; r < 16; ++r) {
      int d = db * 32 + (r & 3) + ((r >> 2) << 3) + hi4;
      comb[wv][ql][d] = oo[r];
    }
  }
  __syncthreads();

  // cross-wave combine: thread -> (row, 8 d's); normalize; store f16
  int row = tid >> 3, d0 = (tid & 7) << 3;
  float inv = 1.0f / (rscomb[row] + rscomb[32 + row] + rscomb[64 + row] +
                      rscomb[96 + row]);
  float sum[8] = {};
#pragma unroll
  for (int w = 0; w < 4; ++w) {
    float4 a = *(const float4*)&comb[w][row][d0];
    float4 c = *(const float4*)&comb[w][row][d0 + 4];
    sum[0] += a.x; sum[1] += a.y; sum[2] += a.z; sum[3] += a.w;
    sum[4] += c.x; sum[5] += c.y; sum[6] += c.z; sum[7] += c.w;
  }
  f16x8 o8;
#pragma unroll
  for (int e = 0; e < 8; ++e) o8[e] = (f16)(sum[e] * inv);
  *(f16x8*)&Ab[((size_t)b * 2048 + qw + row) * 768 + h * 64 + d0] = o8;
}

// ---------------- host ----------------
extern "C" void kernel_launch(void* const* d_in, const int* in_sizes, int n_in,
                              void* d_out, int out_size, void* d_ws,
                              size_t ws_size, hipStream_t stream) {
  const float* x = (const float*)d_in[0];
  const float* Wqkv = (const float*)d_in[1];
  const float* Wproj = (const float*)d_in[2];
  const float* bproj = (const float*)d_in[3];
  float* out = (float*)d_out;
  char* ws = (char*)d_ws;

  f16* xb     = (f16*)(ws + 0);         // 4096x768
  f16* WqkvT  = (f16*)(ws + 6291456);   // 2304x768
  f16* WprojT = (f16*)(ws + 9830400);   // 768x768
  f16* Qb     = (f16*)(ws + 11010048);  // 24x131072 (fragment layout)
  f16* Kb     = (f16*)(ws + 17301504);  // 24x131072 (fragment layout)
  f16* Vtb    = (f16*)(ws + 23592960);  // 24x131072 (fragment layout)
  f16* Ab     = (f16*)(ws + 29884416);  // 4096x768
  // total 36,175,872 B

  k_prep<<<1344, 256, 0, stream>>>(x, xb, Wqkv, WqkvT, Wproj, WprojT);
  k_gemm<<<dim3(32, 18), 256, 0, stream>>>(xb, WqkvT, 4096, 2304, 768, 0, Qb,
                                           Kb, Vtb, nullptr, nullptr);
  k_attn<<<dim3(24, 64), 256, 0, stream>>>(Qb, Kb, Vtb, Ab);
  k_gemm<<<dim3(32, 6), 256, 0, stream>>>(Ab, WprojT, 4096, 768, 768, 1,
                                          nullptr, nullptr, nullptr, bproj, out);
}

// Round 20
// 81.795 us; speedup vs baseline: 1.6989x; 1.0711x over previous
//
#include <hip/hip_runtime.h>

typedef _Float16 f16;
typedef __attribute__((ext_vector_type(4))) _Float16 f16x4;
typedef __attribute__((ext_vector_type(8))) _Float16 f16x8;
typedef __attribute__((ext_vector_type(2))) __fp16 fp16x2;
typedef __attribute__((ext_vector_type(4))) float f32x4;
typedef __attribute__((ext_vector_type(16))) float f32x16;
typedef __attribute__((ext_vector_type(2))) unsigned u32x2;

#define MFMA16(a, b, c) __builtin_amdgcn_mfma_f32_16x16x32_f16((a), (b), (c), 0, 0, 0)
#define MFMA32(a, b, c) __builtin_amdgcn_mfma_f32_32x32x16_f16((a), (b), (c), 0, 0, 0)

__device__ __forceinline__ void gload_lds16(const void* g, void* l) {
  __builtin_amdgcn_global_load_lds(
      (const __attribute__((address_space(1))) void*)g,
      (__attribute__((address_space(3))) void*)l, 16, 0, 0);
}

__device__ __forceinline__ unsigned pkrtz(float lo, float hi) {
  union { fp16x2 h; unsigned u; } cv;
  cv.h = __builtin_amdgcn_cvt_pkrtz(lo, hi);
  return cv.u;
}

// exchange halves: a' = [a.lo | b.lo_from_partner], b' = [a.hi_from_partner | b.hi]
__device__ __forceinline__ void xch(unsigned& a, unsigned& b) {
#if __has_builtin(__builtin_amdgcn_permlane32_swap)
  u32x2 r = __builtin_amdgcn_permlane32_swap(a, b, false, false);
  a = r[0];
  b = r[1];
#else
  unsigned sa = __shfl_xor((int)a, 32), sb = __shfl_xor((int)b, 32);
  bool hi = (threadIdx.x & 32) != 0;
  unsigned x = hi ? sb : a;
  unsigned y = hi ? b : sa;
  a = x;
  b = y;
#endif
}

// fragment-layout index helpers (Q/K share one form; V has its own).
// K/Q: lane l of 32-key block kb32, dword-col c  ->  elements
//   [t = kb32*32 + (l&31)][d = c*16 + (l>>5)*8 + e]
__device__ __forceinline__ size_t kq_idx(int t, int d) {
  return (size_t)(((t >> 5) * 4 + (d >> 4)) * 512 +
                  (((t & 31) | (((d >> 3) & 1) << 5)) * 8) + (d & 7));
}
// V: lane l of frag (kb32, db, ks) -> [d = db*32 + (l&31)][t = kb32*32 + ks*16 + (l>>5)*8 + e]
__device__ __forceinline__ size_t v_idx(int t, int d) {
  return (size_t)(((((t >> 5) * 2 + (d >> 5)) * 2 + ((t >> 4) & 1)) * 512) +
                  (((d & 31) | (((t >> 3) & 1) << 5)) * 8) + (t & 7));
}

// ------- fused prep: convert x -> f16, transpose Wqkv & Wproj -> [N][K] f16 -------
__global__ __launch_bounds__(256) void k_prep(
    const float* __restrict__ x, f16* __restrict__ xb,
    const float* __restrict__ Wq, f16* __restrict__ WqT,
    const float* __restrict__ Wp, f16* __restrict__ WpT) {
  __shared__ float tile[64][65];
  int bid = blockIdx.x;
  if (bid < 768) {
    int i = bid * 256 + threadIdx.x;
#pragma unroll
    for (int it = 0; it < 4; ++it, i += 768 * 256) {
      float4 v = ((const float4*)x)[i];
      f16x4 o;
      o[0] = (f16)v.x; o[1] = (f16)v.y; o[2] = (f16)v.z; o[3] = (f16)v.w;
      ((f16x4*)xb)[i] = o;
    }
    return;
  }
  const float* in; f16* out; int N, n0, k0;
  if (bid < 1200) {
    int t = bid - 768;
    in = Wq; out = WqT; N = 2304;
    n0 = (t % 36) * 64; k0 = (t / 36) * 64;
  } else {
    int t = bid - 1200;
    in = Wp; out = WpT; N = 768;
    n0 = (t % 12) * 64; k0 = (t / 12) * 64;
  }
  int c = threadIdx.x & 63, r4 = threadIdx.x >> 6;
#pragma unroll
  for (int i = 0; i < 16; ++i) {
    int r = i * 4 + r4;
    tile[r][c] = in[(size_t)(k0 + r) * N + n0 + c];
  }
  __syncthreads();
#pragma unroll
  for (int i = 0; i < 16; ++i) {
    int r = i * 4 + r4;
    out[(size_t)(n0 + r) * 768 + k0 + c] = (f16)tile[c][r];
  }
}

// --------- 128x128 f16 MFMA GEMM, BK=64, XOR-swizzled LDS, 2-phase dbuf ---------
// (T1 XCD swizzle REVERTED: r19 A/B showed −5.5us on this L3-resident problem —
//  natural id order already gives B-panel adjacency; T1's gain needs HBM-bound.)
// LDS logical layout [128 rows][8 chunks of 16B]; physical chunk = c ^ (row&7);
// swizzle applied on the GLOBAL source at stage time + ds_read addr (m201).
// Pipeline (T3-minimal): stage(buf^1, t+1) issued BEFORE compute(buf[t]).
// mode 0: scatter to FRAGMENT-layout Qf/Kf/Vf; mode 1: out = acc + bias (fp32)
__global__ __launch_bounds__(256) void k_gemm(
    const f16* __restrict__ A, const f16* __restrict__ BT,
    int M, int N, int K, int mode,
    f16* __restrict__ Qo, f16* __restrict__ Ko, f16* __restrict__ Vt,
    const float* __restrict__ bias, float* __restrict__ out) {
  __shared__ f16 As[2][128 * 64];
  __shared__ f16 Bs[2][128 * 64];
  int tid = threadIdx.x;
  int wv = tid >> 6;
  int lane = tid & 63;
  int lr = lane & 15, lc = lane >> 4;
  int m0 = blockIdx.x * 128, n0 = blockIdx.y * 128;
  int wm = (wv >> 1) * 64, wn = (wv & 1) * 64;
  f32x4 acc[4][4] = {};
  int nK = K >> 6;  // BK = 64

  // stage one 128x64 tile pair into buffer bf (8 gload_lds16 issues/thread)
  auto stage = [&](int bf, int k0) {
#pragma unroll
    for (int i = 0; i < 4; ++i) {
      int g = i * 256 + tid;
      int row = g >> 3;
      int ch = (g & 7) ^ (row & 7);
      gload_lds16(A + (size_t)(m0 + row) * K + k0 + ch * 8,
                  As[bf] + (size_t)(i * 256 + (tid & 192)) * 8);
    }
#pragma unroll
    for (int i = 0; i < 4; ++i) {
      int g = i * 256 + tid;
      int row = g >> 3;
      int ch = (g & 7) ^ (row & 7);
      gload_lds16(BT + (size_t)(n0 + row) * K + k0 + ch * 8,
                  Bs[bf] + (size_t)(i * 256 + (tid & 192)) * 8);
    }
  };

  stage(0, 0);
  __syncthreads();  // drain prologue stage
  int cur = 0;
  for (int kt = 0; kt < nK; ++kt) {
    // issue next tile's loads first — latency hides under this tile's compute
    if (kt + 1 < nK) stage(cur ^ 1, (kt + 1) << 6);
    // two K=32 sub-steps; fragment read chunk = ((kh<<2)|lc) ^ (lr&7)
#pragma unroll
    for (int kh = 0; kh < 2; ++kh) {
      f16x8 af[4], bf[4];
      int csw = (((kh << 2) | lc) ^ (lr & 7)) << 3;
#pragma unroll
      for (int mi = 0; mi < 4; ++mi)
        af[mi] = *(const f16x8*)&As[cur][(wm + mi * 16 + lr) * 64 + csw];
#pragma unroll
      for (int ni = 0; ni < 4; ++ni)
        bf[ni] = *(const f16x8*)&Bs[cur][(wn + ni * 16 + lr) * 64 + csw];
#pragma unroll
      for (int mi = 0; mi < 4; ++mi)
#pragma unroll
        for (int ni = 0; ni < 4; ++ni)
          acc[mi][ni] = MFMA16(af[mi], bf[ni], acc[mi][ni]);
    }
    __syncthreads();  // drains prefetch (post-compute) + protects buf reuse
    cur ^= 1;
  }
  if (mode == 0) {
#pragma unroll
    for (int ni = 0; ni < 4; ++ni) {
      int col = n0 + wn + ni * 16 + lr;
      int s = col / 768;
      int hh = (col - s * 768) >> 6;
      int d = col & 63;
      if (s == 2) {
#pragma unroll
        for (int mi = 0; mi < 4; ++mi) {
          int row0 = m0 + wm + mi * 16 + lc * 4;
          int b = row0 >> 11, t = row0 & 2047;
          f16x4 tv;
#pragma unroll
          for (int r = 0; r < 4; ++r) tv[r] = (f16)acc[mi][ni][r];
          // 4 consecutive t = 4 consecutive e within one fragment octet
          *(f16x4*)&Vt[((size_t)(b * 12 + hh) << 17) | v_idx(t, d)] = tv;
        }
      } else {
        f16* dst = (s == 0) ? Qo : Ko;
#pragma unroll
        for (int mi = 0; mi < 4; ++mi)
#pragma unroll
          for (int r = 0; r < 4; ++r) {
            int row = m0 + wm + mi * 16 + lc * 4 + r;
            int b = row >> 11, t = row & 2047;
            dst[((size_t)(b * 12 + hh) << 17) | kq_idx(t, d)] =
                (f16)acc[mi][ni][r];
          }
      }
    }
  } else {
#pragma unroll
    for (int ni = 0; ni < 4; ++ni) {
      int col = n0 + wn + ni * 16 + lr;
      float bv = bias[col];
#pragma unroll
      for (int mi = 0; mi < 4; ++mi)
#pragma unroll
        for (int r = 0; r < 4; ++r) {
          int row = m0 + wm + mi * 16 + lc * 4 + r;
          out[(size_t)row * 768 + col] = acc[mi][ni][r] + bv;
        }
    }
  }
}

// ---- causal softplus-normalized attention: 4-wave split-K, P in registers ----
// Block (bh, qt), 256 threads. Wave wv handles 64-key tiles kt = wv, wv+4, ...
// Q/K/V live in FRAGMENT-layout buffers -> every load is base + lane*16B,
// fully coalesced (1 KB/instr, 8 cache lines instead of 32 — the r13 fix).
// Swapped 32x32 MFMA body: S = mfma32(A=K, B=Q); softplus+rowsum in-lane;
// P->f16 via cvt_pkrtz + permlane32_swap; O^T += mfma32(A=V-frag, B=P).
// K prefetched right after QK^T; all 8 V frags issued up-front (MLP).
// LDS untouched in the k-loop; single combine at the end (comb[4][32][68]).
// launch_bounds (256,3): bound 4 forces 64 arch-VGPRs -> catastrophic spills
// (r12, r18: FETCH 95-120MB, +50us). This body NEEDS ~110 regs; 3 is the max.
__global__ __launch_bounds__(256, 3) void k_attn(const f16* __restrict__ Q,
                                                 const f16* __restrict__ K,
                                                 const f16* __restrict__ Vt,
                                                 f16* __restrict__ Ab) {
  __shared__ __align__(16) char smem[35328];
  float (*comb)[32][68] = (float(*)[32][68])smem;  // [wv][q][d]
  float* rscomb = (float*)(smem + 34816);          // [wv][q]
  int tid = threadIdx.x, wv = tid >> 6, lane = tid & 63;
  int ql = lane & 31;
  int hi = lane >> 5;
  int hi4 = hi << 2;
  int bh = blockIdx.x;
  int qt = 63 - (int)blockIdx.y;  // heavy blocks dispatch first
  int qw = qt * 32;
  int b = bh / 12, h = bh - b * 12;
  const f16* Qp = Q + ((size_t)bh << 17);
  const f16* Kp = K + ((size_t)bh << 17);
  const f16* Vp = Vt + ((size_t)bh << 17);
  int l8 = lane * 8;

  const f16 a16 = (f16)0.18033688f;  // 0.125 * log2(e): fold scale into Q
  f16x8 qf[4];
#pragma unroll
  for (int c = 0; c < 4; ++c) {
    qf[c] = *(const f16x8*)&Qp[((qw >> 5) * 4 + c) * 512 + l8];
    qf[c] *= a16;
  }

  f32x16 o0 = {}, o1 = {};  // O^T[d = db*32 + crow(r,hi)][q] partials
  float rsp[4] = {0.f, 0.f, 0.f, 0.f};
  f16x8 kf[2][4];

  auto loadK = [&](int kb) {
#pragma unroll
    for (int kblk = 0; kblk < 2; ++kblk)
#pragma unroll
      for (int c = 0; c < 4; ++c)
        kf[kblk][c] =
            *(const f16x8*)&Kp[(((kb >> 5) + kblk) * 4 + c) * 512 + l8];
  };
  auto vfrag = [&](int kb32, int db, int ks) {
    return *(const f16x8*)&Vp[((kb32 * 2 + db) * 2 + ks) * 512 + l8];
  };

  // softplus: w' = log2(1+2^z) (uniform ln2 cancels in w/rowsum), in-place.
  auto spblk = [&](f32x16& sv, bool domask) {
#pragma unroll
    for (int r = 0; r < 16; ++r) {
      float z = sv[r];
      float w = __builtin_amdgcn_logf(1.f + __builtin_amdgcn_exp2f(z));
      if (domask) {
        int kl = (r & 3) + ((r >> 2) << 3) + hi4;
        w = (kl <= ql) ? w : 0.f;
      }
      rsp[r & 3] += w;
      sv[r] = w;
    }
  };

  // pack P to f16, exchange halves, feed PV for one 32-key block
  auto pvblk = [&](f32x16& sv, f16x8& vfa, f16x8& vfa2, f16x8& vfb,
                   f16x8& vfb2) {
#pragma unroll
    for (int ks = 0; ks < 2; ++ks) {
      unsigned Aw = pkrtz(sv[ks * 8 + 0], sv[ks * 8 + 1]);
      unsigned Bw = pkrtz(sv[ks * 8 + 2], sv[ks * 8 + 3]);
      unsigned Cw = pkrtz(sv[ks * 8 + 4], sv[ks * 8 + 5]);
      unsigned Dw = pkrtz(sv[ks * 8 + 6], sv[ks * 8 + 7]);
      xch(Aw, Cw);
      xch(Bw, Dw);
      union { unsigned u[4]; f16x8 v; } pf;
      pf.u[0] = Aw; pf.u[1] = Bw; pf.u[2] = Cw; pf.u[3] = Dw;
      o0 = MFMA32(ks ? vfa2 : vfa, pf.v, o0);
      o1 = MFMA32(ks ? vfb2 : vfb, pf.v, o1);
    }
  };

  auto tile = [&](int kb, bool dob1, bool mask, int kbn) {
    // 1. QK^T on prefetched kf (kf dead after this)
    f32x16 s0 = {}, s1 = {};
#pragma unroll
    for (int c = 0; c < 4; ++c) s0 = MFMA32(kf[0][c], qf[c], s0);
    if (dob1) {
#pragma unroll
      for (int c = 0; c < 4; ++c) s1 = MFMA32(kf[1][c], qf[c], s1);
    }
    // 2. prefetch this wave's next K immediately (longest latency to hide)
    if (kbn >= 0) loadK(kbn);
    // 3. all 8 V fragments issued up-front (coalesced; MLP)
    int kb32 = kb >> 5;
    f16x8 va0 = vfrag(kb32, 0, 0), va1 = vfrag(kb32, 0, 1);
    f16x8 vb0 = vfrag(kb32, 1, 0), vb1 = vfrag(kb32, 1, 1);
    f16x8 wa0, wa1, wb0, wb1;
    if (dob1) {
      wa0 = vfrag(kb32 + 1, 0, 0); wa1 = vfrag(kb32 + 1, 0, 1);
      wb0 = vfrag(kb32 + 1, 1, 0); wb1 = vfrag(kb32 + 1, 1, 1);
    }
    // 4. softplus + pack + PV per 32-key block
    spblk(s0, mask && !dob1);
    pvblk(s0, va0, va1, vb0, vb1);
    if (dob1) {
      spblk(s1, mask);
      pvblk(s1, wa0, wa1, wb0, wb1);
    }
  };

  int dt = qt >> 1;     // diagonal 64-tile index
  bool odd = (qt & 1);  // odd: kblk0 full, kblk1 diag; even: kblk0 diag only
  int nfull = (dt > wv) ? ((dt - wv + 3) >> 2) : 0;  // full tiles for this wave
  bool owndiag = ((dt & 3) == wv);
  if (nfull > 0 || owndiag) loadK(nfull > 0 ? wv * 64 : dt * 64);
  for (int i = 0; i < nfull; ++i) {
    int kb = (wv + 4 * i) * 64;
    int kbn = (i + 1 < nfull) ? kb + 256 : (owndiag ? dt * 64 : -1);
    tile(kb, true, false, kbn);
  }
  if (owndiag) tile(dt * 64, odd, true, -1);

  // per-wave rowsum for q=ql (combine the two key-halves)
  float rs = (rsp[0] + rsp[1]) + (rsp[2] + rsp[3]);
  rs += __shfl_xor(rs, 32);

  // deposit per-wave partials (LDS first touched here; no prior barrier needed)
  if (hi == 0) rscomb[wv * 32 + ql] = rs;
#pragma unroll
  for (int db = 0; db < 2; ++db) {
    const f32x16& oo = db ? o1 : o0;
#pragma unroll
    for (int r = 0; r < 16; ++r) {
      int d = db * 32 + (r & 3) + ((r >> 2) << 3) + hi4;
      comb[wv][ql][d] = oo[r];
    }
  }
  __syncthreads();

  // cross-wave combine: thread -> (row, 8 d's); normalize; store f16
  int row = tid >> 3, d0 = (tid & 7) << 3;
  float inv = 1.0f / (rscomb[row] + rscomb[32 + row] + rscomb[64 + row] +
                      rscomb[96 + row]);
  float sum[8] = {};
#pragma unroll
  for (int w = 0; w < 4; ++w) {
    float4 a = *(const float4*)&comb[w][row][d0];
    float4 c = *(const float4*)&comb[w][row][d0 + 4];
    sum[0] += a.x; sum[1] += a.y; sum[2] += a.z; sum[3] += a.w;
    sum[4] += c.x; sum[5] += c.y; sum[6] += c.z; sum[7] += c.w;
  }
  f16x8 o8;
#pragma unroll
  for (int e = 0; e < 8; ++e) o8[e] = (f16)(sum[e] * inv);
  *(f16x8*)&Ab[((size_t)b * 2048 + qw + row) * 768 + h * 64 + d0] = o8;
}

// ---------------- host ----------------
extern "C" void kernel_launch(void* const* d_in, const int* in_sizes, int n_in,
                              void* d_out, int out_size, void* d_ws,
                              size_t ws_size, hipStream_t stream) {
  const float* x = (const float*)d_in[0];
  const float* Wqkv = (const float*)d_in[1];
  const float* Wproj = (const float*)d_in[2];
  const float* bproj = (const float*)d_in[3];
  float* out = (float*)d_out;
  char* ws = (char*)d_ws;

  f16* xb     = (f16*)(ws + 0);         // 4096x768
  f16* WqkvT  = (f16*)(ws + 6291456);   // 2304x768
  f16* WprojT = (f16*)(ws + 9830400);   // 768x768
  f16* Qb     = (f16*)(ws + 11010048);  // 24x131072 (fragment layout)
  f16* Kb     = (f16*)(ws + 17301504);  // 24x131072 (fragment layout)
  f16* Vtb    = (f16*)(ws + 23592960);  // 24x131072 (fragment layout)
  f16* Ab     = (f16*)(ws + 29884416);  // 4096x768
  // total 36,175,872 B

  k_prep<<<1344, 256, 0, stream>>>(x, xb, Wqkv, WqkvT, Wproj, WprojT);
  k_gemm<<<dim3(32, 18), 256, 0, stream>>>(xb, WqkvT, 4096, 2304, 768, 0, Qb,
                                           Kb, Vtb, nullptr, nullptr);
  k_attn<<<dim3(24, 64), 256, 0, stream>>>(Qb, Kb, Vtb, Ab);
  k_gemm<<<dim3(32, 6), 256, 0, stream>>>(Ab, WprojT, 4096, 768, 768, 1,
                                          nullptr, nullptr, nullptr, bproj, out);
}

// Round 21
// 80.374 us; speedup vs baseline: 1.7290x; 1.0177x over previous
//
#include <hip/hip_runtime.h>

typedef _Float16 f16;
typedef __attribute__((ext_vector_type(4))) _Float16 f16x4;
typedef __attribute__((ext_vector_type(8))) _Float16 f16x8;
typedef __attribute__((ext_vector_type(2))) __fp16 fp16x2;
typedef __attribute__((ext_vector_type(4))) float f32x4;
typedef __attribute__((ext_vector_type(16))) float f32x16;
typedef __attribute__((ext_vector_type(2))) unsigned u32x2;

#define MFMA16(a, b, c) __builtin_amdgcn_mfma_f32_16x16x32_f16((a), (b), (c), 0, 0, 0)
#define MFMA32(a, b, c) __builtin_amdgcn_mfma_f32_32x32x16_f16((a), (b), (c), 0, 0, 0)

__device__ __forceinline__ void gload_lds16(const void* g, void* l) {
  __builtin_amdgcn_global_load_lds(
      (const __attribute__((address_space(1))) void*)g,
      (__attribute__((address_space(3))) void*)l, 16, 0, 0);
}

__device__ __forceinline__ unsigned pkrtz(float lo, float hi) {
  union { fp16x2 h; unsigned u; } cv;
  cv.h = __builtin_amdgcn_cvt_pkrtz(lo, hi);
  return cv.u;
}

// exchange halves: a' = [a.lo | b.lo_from_partner], b' = [a.hi_from_partner | b.hi]
__device__ __forceinline__ void xch(unsigned& a, unsigned& b) {
#if __has_builtin(__builtin_amdgcn_permlane32_swap)
  u32x2 r = __builtin_amdgcn_permlane32_swap(a, b, false, false);
  a = r[0];
  b = r[1];
#else
  unsigned sa = __shfl_xor((int)a, 32), sb = __shfl_xor((int)b, 32);
  bool hi = (threadIdx.x & 32) != 0;
  unsigned x = hi ? sb : a;
  unsigned y = hi ? b : sa;
  a = x;
  b = y;
#endif
}

// fragment-layout index helpers (Q/K share one form; V has its own).
// K/Q: lane l of 32-key block kb32, dword-col c  ->  elements
//   [t = kb32*32 + (l&31)][d = c*16 + (l>>5)*8 + e]
__device__ __forceinline__ size_t kq_idx(int t, int d) {
  return (size_t)(((t >> 5) * 4 + (d >> 4)) * 512 +
                  (((t & 31) | (((d >> 3) & 1) << 5)) * 8) + (d & 7));
}
// V: lane l of frag (kb32, db, ks) -> [d = db*32 + (l&31)][t = kb32*32 + ks*16 + (l>>5)*8 + e]
__device__ __forceinline__ size_t v_idx(int t, int d) {
  return (size_t)(((((t >> 5) * 2 + (d >> 5)) * 2 + ((t >> 4) & 1)) * 512) +
                  (((d & 31) | (((t >> 3) & 1) << 5)) * 8) + (t & 7));
}

// ------- fused prep: convert x -> f16, transpose Wqkv & Wproj -> [N][K] f16 -------
__global__ __launch_bounds__(256) void k_prep(
    const float* __restrict__ x, f16* __restrict__ xb,
    const float* __restrict__ Wq, f16* __restrict__ WqT,
    const float* __restrict__ Wp, f16* __restrict__ WpT) {
  __shared__ float tile[64][65];
  int bid = blockIdx.x;
  if (bid < 768) {
    int i = bid * 256 + threadIdx.x;
#pragma unroll
    for (int it = 0; it < 4; ++it, i += 768 * 256) {
      float4 v = ((const float4*)x)[i];
      f16x4 o;
      o[0] = (f16)v.x; o[1] = (f16)v.y; o[2] = (f16)v.z; o[3] = (f16)v.w;
      ((f16x4*)xb)[i] = o;
    }
    return;
  }
  const float* in; f16* out; int N, n0, k0;
  if (bid < 1200) {
    int t = bid - 768;
    in = Wq; out = WqT; N = 2304;
    n0 = (t % 36) * 64; k0 = (t / 36) * 64;
  } else {
    int t = bid - 1200;
    in = Wp; out = WpT; N = 768;
    n0 = (t % 12) * 64; k0 = (t / 12) * 64;
  }
  int c = threadIdx.x & 63, r4 = threadIdx.x >> 6;
#pragma unroll
  for (int i = 0; i < 16; ++i) {
    int r = i * 4 + r4;
    tile[r][c] = in[(size_t)(k0 + r) * N + n0 + c];
  }
  __syncthreads();
#pragma unroll
  for (int i = 0; i < 16; ++i) {
    int r = i * 4 + r4;
    out[(size_t)(n0 + r) * 768 + k0 + c] = (f16)tile[c][r];
  }
}

// --------- 128x128 f16 MFMA GEMM, BK=64, XOR-swizzled LDS ---------
// 2-phase dbuf with T4 COUNTED vmcnt (AITER pattern): tiles t and t+1 staged;
// per iter: vmcnt(8) waits only the OLDEST 8 loads (tile t) — tile t+1's stay
// in flight across BOTH raw s_barriers; stage t+2 after compute+barrier2.
// Prefetch gets a full iteration (~600cyc) to land instead of one compute phase.
// LDS logical layout [128 rows][8 chunks of 16B]; physical chunk = c ^ (row&7);
// swizzle applied on the GLOBAL source at stage time + ds_read addr (m201).
// mode 0: scatter to FRAGMENT-layout Qf/Kf/Vf; mode 1: out = acc + bias (fp32)
__global__ __launch_bounds__(256) void k_gemm(
    const f16* __restrict__ A, const f16* __restrict__ BT,
    int M, int N, int K, int mode,
    f16* __restrict__ Qo, f16* __restrict__ Ko, f16* __restrict__ Vt,
    const float* __restrict__ bias, float* __restrict__ out) {
  __shared__ f16 As[2][128 * 64];
  __shared__ f16 Bs[2][128 * 64];
  int tid = threadIdx.x;
  int wv = tid >> 6;
  int lane = tid & 63;
  int lr = lane & 15, lc = lane >> 4;
  int m0 = blockIdx.x * 128, n0 = blockIdx.y * 128;
  int wm = (wv >> 1) * 64, wn = (wv & 1) * 64;
  f32x4 acc[4][4] = {};
  int nK = K >> 6;  // BK = 64

  // stage one 128x64 tile pair into buffer bf (8 gload_lds16 issues/thread)
  auto stage = [&](int bf, int k0) {
#pragma unroll
    for (int i = 0; i < 4; ++i) {
      int g = i * 256 + tid;
      int row = g >> 3;
      int ch = (g & 7) ^ (row & 7);
      gload_lds16(A + (size_t)(m0 + row) * K + k0 + ch * 8,
                  As[bf] + (size_t)(i * 256 + (tid & 192)) * 8);
    }
#pragma unroll
    for (int i = 0; i < 4; ++i) {
      int g = i * 256 + tid;
      int row = g >> 3;
      int ch = (g & 7) ^ (row & 7);
      gload_lds16(BT + (size_t)(n0 + row) * K + k0 + ch * 8,
                  Bs[bf] + (size_t)(i * 256 + (tid & 192)) * 8);
    }
  };

  // prologue: 2 tiles in flight (16 VMEM ops/thread)
  stage(0, 0);
  if (nK > 1) stage(1, 1 << 6);
  int cur = 0;
  for (int kt = 0; kt < nK; ++kt) {
    // counted wait: retire the OLDEST 8 (tile kt); keep tile kt+1's in flight
    if (kt + 1 < nK)
      asm volatile("s_waitcnt vmcnt(8)" ::: "memory");
    else
      asm volatile("s_waitcnt vmcnt(0)" ::: "memory");
    __builtin_amdgcn_s_barrier();  // all waves' tile-kt loads landed
    // two K=32 sub-steps; fragment read chunk = ((kh<<2)|lc) ^ (lr&7)
#pragma unroll
    for (int kh = 0; kh < 2; ++kh) {
      f16x8 af[4], bf[4];
      int csw = (((kh << 2) | lc) ^ (lr & 7)) << 3;
#pragma unroll
      for (int mi = 0; mi < 4; ++mi)
        af[mi] = *(const f16x8*)&As[cur][(wm + mi * 16 + lr) * 64 + csw];
#pragma unroll
      for (int ni = 0; ni < 4; ++ni)
        bf[ni] = *(const f16x8*)&Bs[cur][(wn + ni * 16 + lr) * 64 + csw];
#pragma unroll
      for (int mi = 0; mi < 4; ++mi)
#pragma unroll
        for (int ni = 0; ni < 4; ++ni)
          acc[mi][ni] = MFMA16(af[mi], bf[ni], acc[mi][ni]);
    }
    // ds_reads retired before other waves may overwrite this buffer
    asm volatile("s_waitcnt lgkmcnt(0)" ::: "memory");
    __builtin_amdgcn_s_barrier();  // no vmem drain: prefetch stays in flight
    if (kt + 2 < nK) stage(cur, (kt + 2) << 6);  // refill the freed buffer
    cur ^= 1;
  }
  if (mode == 0) {
#pragma unroll
    for (int ni = 0; ni < 4; ++ni) {
      int col = n0 + wn + ni * 16 + lr;
      int s = col / 768;
      int hh = (col - s * 768) >> 6;
      int d = col & 63;
      if (s == 2) {
#pragma unroll
        for (int mi = 0; mi < 4; ++mi) {
          int row0 = m0 + wm + mi * 16 + lc * 4;
          int b = row0 >> 11, t = row0 & 2047;
          f16x4 tv;
#pragma unroll
          for (int r = 0; r < 4; ++r) tv[r] = (f16)acc[mi][ni][r];
          // 4 consecutive t = 4 consecutive e within one fragment octet
          *(f16x4*)&Vt[((size_t)(b * 12 + hh) << 17) | v_idx(t, d)] = tv;
        }
      } else {
        f16* dst = (s == 0) ? Qo : Ko;
#pragma unroll
        for (int mi = 0; mi < 4; ++mi)
#pragma unroll
          for (int r = 0; r < 4; ++r) {
            int row = m0 + wm + mi * 16 + lc * 4 + r;
            int b = row >> 11, t = row & 2047;
            dst[((size_t)(b * 12 + hh) << 17) | kq_idx(t, d)] =
                (f16)acc[mi][ni][r];
          }
      }
    }
  } else {
#pragma unroll
    for (int ni = 0; ni < 4; ++ni) {
      int col = n0 + wn + ni * 16 + lr;
      float bv = bias[col];
#pragma unroll
      for (int mi = 0; mi < 4; ++mi)
#pragma unroll
        for (int r = 0; r < 4; ++r) {
          int row = m0 + wm + mi * 16 + lc * 4 + r;
          out[(size_t)row * 768 + col] = acc[mi][ni][r] + bv;
        }
    }
  }
}

// ---- causal softplus-normalized attention: 4-wave split-K, P in registers ----
// Block (bh, qt), 256 threads. Wave wv handles 64-key tiles kt = wv, wv+4, ...
// Q/K/V live in FRAGMENT-layout buffers -> every load is base + lane*16B,
// fully coalesced (1 KB/instr, 8 cache lines instead of 32 — the r13 fix).
// Swapped 32x32 MFMA body: S = mfma32(A=K, B=Q); softplus+rowsum in-lane;
// P->f16 via cvt_pkrtz + permlane32_swap; O^T += mfma32(A=V-frag, B=P).
// K prefetched right after QK^T; all 8 V frags issued up-front (MLP).
// LDS untouched in the k-loop; single combine at the end (comb[4][32][68]).
// launch_bounds (256,3): bound 4 forces 64 arch-VGPRs -> catastrophic spills
// (r12, r18: FETCH 95-120MB, +50us). This body NEEDS ~110 regs; 3 is the max.
__global__ __launch_bounds__(256, 3) void k_attn(const f16* __restrict__ Q,
                                                 const f16* __restrict__ K,
                                                 const f16* __restrict__ Vt,
                                                 f16* __restrict__ Ab) {
  __shared__ __align__(16) char smem[35328];
  float (*comb)[32][68] = (float(*)[32][68])smem;  // [wv][q][d]
  float* rscomb = (float*)(smem + 34816);          // [wv][q]
  int tid = threadIdx.x, wv = tid >> 6, lane = tid & 63;
  int ql = lane & 31;
  int hi = lane >> 5;
  int hi4 = hi << 2;
  int bh = blockIdx.x;
  int qt = 63 - (int)blockIdx.y;  // heavy blocks dispatch first
  int qw = qt * 32;
  int b = bh / 12, h = bh - b * 12;
  const f16* Qp = Q + ((size_t)bh << 17);
  const f16* Kp = K + ((size_t)bh << 17);
  const f16* Vp = Vt + ((size_t)bh << 17);
  int l8 = lane * 8;

  const f16 a16 = (f16)0.18033688f;  // 0.125 * log2(e): fold scale into Q
  f16x8 qf[4];
#pragma unroll
  for (int c = 0; c < 4; ++c) {
    qf[c] = *(const f16x8*)&Qp[((qw >> 5) * 4 + c) * 512 + l8];
    qf[c] *= a16;
  }

  f32x16 o0 = {}, o1 = {};  // O^T[d = db*32 + crow(r,hi)][q] partials
  float rsp[4] = {0.f, 0.f, 0.f, 0.f};
  f16x8 kf[2][4];

  auto loadK = [&](int kb) {
#pragma unroll
    for (int kblk = 0; kblk < 2; ++kblk)
#pragma unroll
      for (int c = 0; c < 4; ++c)
        kf[kblk][c] =
            *(const f16x8*)&Kp[(((kb >> 5) + kblk) * 4 + c) * 512 + l8];
  };
  auto vfrag = [&](int kb32, int db, int ks) {
    return *(const f16x8*)&Vp[((kb32 * 2 + db) * 2 + ks) * 512 + l8];
  };

  // softplus: w' = log2(1+2^z) (uniform ln2 cancels in w/rowsum), in-place.
  auto spblk = [&](f32x16& sv, bool domask) {
#pragma unroll
    for (int r = 0; r < 16; ++r) {
      float z = sv[r];
      float w = __builtin_amdgcn_logf(1.f + __builtin_amdgcn_exp2f(z));
      if (domask) {
        int kl = (r & 3) + ((r >> 2) << 3) + hi4;
        w = (kl <= ql) ? w : 0.f;
      }
      rsp[r & 3] += w;
      sv[r] = w;
    }
  };

  // pack P to f16, exchange halves, feed PV for one 32-key block
  auto pvblk = [&](f32x16& sv, f16x8& vfa, f16x8& vfa2, f16x8& vfb,
                   f16x8& vfb2) {
#pragma unroll
    for (int ks = 0; ks < 2; ++ks) {
      unsigned Aw = pkrtz(sv[ks * 8 + 0], sv[ks * 8 + 1]);
      unsigned Bw = pkrtz(sv[ks * 8 + 2], sv[ks * 8 + 3]);
      unsigned Cw = pkrtz(sv[ks * 8 + 4], sv[ks * 8 + 5]);
      unsigned Dw = pkrtz(sv[ks * 8 + 6], sv[ks * 8 + 7]);
      xch(Aw, Cw);
      xch(Bw, Dw);
      union { unsigned u[4]; f16x8 v; } pf;
      pf.u[0] = Aw; pf.u[1] = Bw; pf.u[2] = Cw; pf.u[3] = Dw;
      o0 = MFMA32(ks ? vfa2 : vfa, pf.v, o0);
      o1 = MFMA32(ks ? vfb2 : vfb, pf.v, o1);
    }
  };

  auto tile = [&](int kb, bool dob1, bool mask, int kbn) {
    // 1. QK^T on prefetched kf (kf dead after this)
    f32x16 s0 = {}, s1 = {};
#pragma unroll
    for (int c = 0; c < 4; ++c) s0 = MFMA32(kf[0][c], qf[c], s0);
    if (dob1) {
#pragma unroll
      for (int c = 0; c < 4; ++c) s1 = MFMA32(kf[1][c], qf[c], s1);
    }
    // 2. prefetch this wave's next K immediately (longest latency to hide)
    if (kbn >= 0) loadK(kbn);
    // 3. all 8 V fragments issued up-front (coalesced; MLP)
    int kb32 = kb >> 5;
    f16x8 va0 = vfrag(kb32, 0, 0), va1 = vfrag(kb32, 0, 1);
    f16x8 vb0 = vfrag(kb32, 1, 0), vb1 = vfrag(kb32, 1, 1);
    f16x8 wa0, wa1, wb0, wb1;
    if (dob1) {
      wa0 = vfrag(kb32 + 1, 0, 0); wa1 = vfrag(kb32 + 1, 0, 1);
      wb0 = vfrag(kb32 + 1, 1, 0); wb1 = vfrag(kb32 + 1, 1, 1);
    }
    // 4. softplus + pack + PV per 32-key block
    spblk(s0, mask && !dob1);
    pvblk(s0, va0, va1, vb0, vb1);
    if (dob1) {
      spblk(s1, mask);
      pvblk(s1, wa0, wa1, wb0, wb1);
    }
  };

  int dt = qt >> 1;     // diagonal 64-tile index
  bool odd = (qt & 1);  // odd: kblk0 full, kblk1 diag; even: kblk0 diag only
  int nfull = (dt > wv) ? ((dt - wv + 3) >> 2) : 0;  // full tiles for this wave
  bool owndiag = ((dt & 3) == wv);
  if (nfull > 0 || owndiag) loadK(nfull > 0 ? wv * 64 : dt * 64);
  for (int i = 0; i < nfull; ++i) {
    int kb = (wv + 4 * i) * 64;
    int kbn = (i + 1 < nfull) ? kb + 256 : (owndiag ? dt * 64 : -1);
    tile(kb, true, false, kbn);
  }
  if (owndiag) tile(dt * 64, odd, true, -1);

  // per-wave rowsum for q=ql (combine the two key-halves)
  float rs = (rsp[0] + rsp[1]) + (rsp[2] + rsp[3]);
  rs += __shfl_xor(rs, 32);

  // deposit per-wave partials (LDS first touched here; no prior barrier needed)
  if (hi == 0) rscomb[wv * 32 + ql] = rs;
#pragma unroll
  for (int db = 0; db < 2; ++db) {
    const f32x16& oo = db ? o1 : o0;
#pragma unroll
    for (int r = 0; r < 16; ++r) {
      int d = db * 32 + (r & 3) + ((r >> 2) << 3) + hi4;
      comb[wv][ql][d] = oo[r];
    }
  }
  __syncthreads();

  // cross-wave combine: thread -> (row, 8 d's); normalize; store f16
  int row = tid >> 3, d0 = (tid & 7) << 3;
  float inv = 1.0f / (rscomb[row] + rscomb[32 + row] + rscomb[64 + row] +
                      rscomb[96 + row]);
  float sum[8] = {};
#pragma unroll
  for (int w = 0; w < 4; ++w) {
    float4 a = *(const float4*)&comb[w][row][d0];
    float4 c = *(const float4*)&comb[w][row][d0 + 4];
    sum[0] += a.x; sum[1] += a.y; sum[2] += a.z; sum[3] += a.w;
    sum[4] += c.x; sum[5] += c.y; sum[6] += c.z; sum[7] += c.w;
  }
  f16x8 o8;
#pragma unroll
  for (int e = 0; e < 8; ++e) o8[e] = (f16)(sum[e] * inv);
  *(f16x8*)&Ab[((size_t)b * 2048 + qw + row) * 768 + h * 64 + d0] = o8;
}

// ---------------- host ----------------
extern "C" void kernel_launch(void* const* d_in, const int* in_sizes, int n_in,
                              void* d_out, int out_size, void* d_ws,
                              size_t ws_size, hipStream_t stream) {
  const float* x = (const float*)d_in[0];
  const float* Wqkv = (const float*)d_in[1];
  const float* Wproj = (const float*)d_in[2];
  const float* bproj = (const float*)d_in[3];
  float* out = (float*)d_out;
  char* ws = (char*)d_ws;

  f16* xb     = (f16*)(ws + 0);         // 4096x768
  f16* WqkvT  = (f16*)(ws + 6291456);   // 2304x768
  f16* WprojT = (f16*)(ws + 9830400);   // 768x768
  f16* Qb     = (f16*)(ws + 11010048);  // 24x131072 (fragment layout)
  f16* Kb     = (f16*)(ws + 17301504);  // 24x131072 (fragment layout)
  f16* Vtb    = (f16*)(ws + 23592960);  // 24x131072 (fragment layout)
  f16* Ab     = (f16*)(ws + 29884416);  // 4096x768
  // total 36,175,872 B

  k_prep<<<1344, 256, 0, stream>>>(x, xb, Wqkv, WqkvT, Wproj, WprojT);
  k_gemm<<<dim3(32, 18), 256, 0, stream>>>(xb, WqkvT, 4096, 2304, 768, 0, Qb,
                                           Kb, Vtb, nullptr, nullptr);
  k_attn<<<dim3(24, 64), 256, 0, stream>>>(Qb, Kb, Vtb, Ab);
  k_gemm<<<dim3(32, 6), 256, 0, stream>>>(Ab, WprojT, 4096, 768, 768, 1,
                                          nullptr, nullptr, nullptr, bproj, out);
}

// Round 22
// 74.383 us; speedup vs baseline: 1.8682x; 1.0805x over previous
//
#include <hip/hip_runtime.h>

typedef _Float16 f16;
typedef __attribute__((ext_vector_type(4))) _Float16 f16x4;
typedef __attribute__((ext_vector_type(8))) _Float16 f16x8;
typedef __attribute__((ext_vector_type(2))) __fp16 fp16x2;
typedef __attribute__((ext_vector_type(4))) float f32x4;
typedef __attribute__((ext_vector_type(16))) float f32x16;
typedef __attribute__((ext_vector_type(2))) unsigned u32x2;

#define MFMA16(a, b, c) __builtin_amdgcn_mfma_f32_16x16x32_f16((a), (b), (c), 0, 0, 0)
#define MFMA32(a, b, c) __builtin_amdgcn_mfma_f32_32x32x16_f16((a), (b), (c), 0, 0, 0)

__device__ __forceinline__ void gload_lds16(const void* g, void* l) {
  __builtin_amdgcn_global_load_lds(
      (const __attribute__((address_space(1))) void*)g,
      (__attribute__((address_space(3))) void*)l, 16, 0, 0);
}

__device__ __forceinline__ unsigned pkrtz(float lo, float hi) {
  union { fp16x2 h; unsigned u; } cv;
  cv.h = __builtin_amdgcn_cvt_pkrtz(lo, hi);
  return cv.u;
}

// exchange halves: a' = [a.lo | b.lo_from_partner], b' = [a.hi_from_partner | b.hi]
__device__ __forceinline__ void xch(unsigned& a, unsigned& b) {
#if __has_builtin(__builtin_amdgcn_permlane32_swap)
  u32x2 r = __builtin_amdgcn_permlane32_swap(a, b, false, false);
  a = r[0];
  b = r[1];
#else
  unsigned sa = __shfl_xor((int)a, 32), sb = __shfl_xor((int)b, 32);
  bool hi = (threadIdx.x & 32) != 0;
  unsigned x = hi ? sb : a;
  unsigned y = hi ? b : sa;
  a = x;
  b = y;
#endif
}

// fragment-layout index helpers (Q/K share one form; V has its own).
// K/Q: lane l of 32-key block kb32, dword-col c  ->  elements
//   [t = kb32*32 + (l&31)][d = c*16 + (l>>5)*8 + e]
__device__ __forceinline__ size_t kq_idx(int t, int d) {
  return (size_t)(((t >> 5) * 4 + (d >> 4)) * 512 +
                  (((t & 31) | (((d >> 3) & 1) << 5)) * 8) + (d & 7));
}
// V: lane l of frag (kb32, db, ks) -> [d = db*32 + (l&31)][t = kb32*32 + ks*16 + (l>>5)*8 + e]
__device__ __forceinline__ size_t v_idx(int t, int d) {
  return (size_t)(((((t >> 5) * 2 + (d >> 5)) * 2 + ((t >> 4) & 1)) * 512) +
                  (((d & 31) | (((t >> 3) & 1) << 5)) * 8) + (t & 7));
}

// ------- fused prep: convert x -> f16, transpose Wqkv & Wproj -> [N][K] f16 -------
__global__ __launch_bounds__(256) void k_prep(
    const float* __restrict__ x, f16* __restrict__ xb,
    const float* __restrict__ Wq, f16* __restrict__ WqT,
    const float* __restrict__ Wp, f16* __restrict__ WpT) {
  __shared__ float tile[64][65];
  int bid = blockIdx.x;
  if (bid < 768) {
    int i = bid * 256 + threadIdx.x;
#pragma unroll
    for (int it = 0; it < 4; ++it, i += 768 * 256) {
      float4 v = ((const float4*)x)[i];
      f16x4 o;
      o[0] = (f16)v.x; o[1] = (f16)v.y; o[2] = (f16)v.z; o[3] = (f16)v.w;
      ((f16x4*)xb)[i] = o;
    }
    return;
  }
  const float* in; f16* out; int N, n0, k0;
  if (bid < 1200) {
    int t = bid - 768;
    in = Wq; out = WqT; N = 2304;
    n0 = (t % 36) * 64; k0 = (t / 36) * 64;
  } else {
    int t = bid - 1200;
    in = Wp; out = WpT; N = 768;
    n0 = (t % 12) * 64; k0 = (t / 12) * 64;
  }
  int c = threadIdx.x & 63, r4 = threadIdx.x >> 6;
#pragma unroll
  for (int i = 0; i < 16; ++i) {
    int r = i * 4 + r4;
    tile[r][c] = in[(size_t)(k0 + r) * N + n0 + c];
  }
  __syncthreads();
#pragma unroll
  for (int i = 0; i < 16; ++i) {
    int r = i * 4 + r4;
    out[(size_t)(n0 + r) * 768 + k0 + c] = (f16)tile[c][r];
  }
}

// --------- BMx128 f16 MFMA GEMM, BK=64, XOR-swizzled LDS, counted-vmcnt dbuf ---------
// BM=64 (both GEMMs): LDS dbuf 48KB -> 3 blocks/CU (was 2 at BM=128); QKV grid
// 1152 blocks (3 resident hide each other's barrier stalls), proj grid 384
// (fully resident). 4 waves as 2Mx2N; wave tile 32x64, acc[2][4].
// T4 counted vmcnt: tiles t,t+1 staged; per iter wait only the OLDEST
// ISS loads; stage t+2 after compute+barrier2 (prefetch spans the whole iter).
// LDS [rows][8 chunks of 16B]; physical chunk = c ^ (row&7), pre-swizzled at
// the GLOBAL source (m201 both-sides rule).
// mode 0: scatter to FRAGMENT-layout Qf/Kf/Vf; mode 1: out = acc + bias (fp32)
template <int BM>
__global__ __launch_bounds__(256) void k_gemm(
    const f16* __restrict__ A, const f16* __restrict__ BT,
    int M, int N, int K, int mode,
    f16* __restrict__ Qo, f16* __restrict__ Ko, f16* __restrict__ Vt,
    const float* __restrict__ bias, float* __restrict__ out) {
  constexpr int MI = BM / 32;       // m-frags per wave (BM=64 -> 2)
  constexpr int AI = BM / 32;       // A stage issues/thread (BM=64 -> 2)
  __shared__ f16 As[2][BM * 64];
  __shared__ f16 Bs[2][128 * 64];
  int tid = threadIdx.x;
  int wv = tid >> 6;
  int lane = tid & 63;
  int lr = lane & 15, lc = lane >> 4;
  int m0 = blockIdx.x * BM, n0 = blockIdx.y * 128;
  int wm = (wv >> 1) * (BM / 2), wn = (wv & 1) * 64;
  f32x4 acc[MI][4] = {};
  int nK = K >> 6;  // BK = 64

  // stage one BMx64 A tile + 128x64 B tile into buffer bf
  auto stage = [&](int bf, int k0) {
#pragma unroll
    for (int i = 0; i < AI; ++i) {
      int g = i * 256 + tid;
      int row = g >> 3;
      int ch = (g & 7) ^ (row & 7);
      gload_lds16(A + (size_t)(m0 + row) * K + k0 + ch * 8,
                  As[bf] + (size_t)(i * 256 + (tid & 192)) * 8);
    }
#pragma unroll
    for (int i = 0; i < 4; ++i) {
      int g = i * 256 + tid;
      int row = g >> 3;
      int ch = (g & 7) ^ (row & 7);
      gload_lds16(BT + (size_t)(n0 + row) * K + k0 + ch * 8,
                  Bs[bf] + (size_t)(i * 256 + (tid & 192)) * 8);
    }
  };

  // prologue: 2 tiles in flight
  stage(0, 0);
  if (nK > 1) stage(1, 1 << 6);
  int cur = 0;
  for (int kt = 0; kt < nK; ++kt) {
    // counted wait: retire only the OLDEST tile's loads; keep t+1's in flight
    if (kt + 1 < nK) {
      if constexpr (BM == 128)
        asm volatile("s_waitcnt vmcnt(8)" ::: "memory");
      else
        asm volatile("s_waitcnt vmcnt(6)" ::: "memory");
    } else {
      asm volatile("s_waitcnt vmcnt(0)" ::: "memory");
    }
    __builtin_amdgcn_s_barrier();  // all waves' tile-kt loads landed
    // two K=32 sub-steps; fragment read chunk = ((kh<<2)|lc) ^ (lr&7)
#pragma unroll
    for (int kh = 0; kh < 2; ++kh) {
      f16x8 af[MI], bf[4];
      int csw = (((kh << 2) | lc) ^ (lr & 7)) << 3;
#pragma unroll
      for (int mi = 0; mi < MI; ++mi)
        af[mi] = *(const f16x8*)&As[cur][(wm + mi * 16 + lr) * 64 + csw];
#pragma unroll
      for (int ni = 0; ni < 4; ++ni)
        bf[ni] = *(const f16x8*)&Bs[cur][(wn + ni * 16 + lr) * 64 + csw];
#pragma unroll
      for (int mi = 0; mi < MI; ++mi)
#pragma unroll
        for (int ni = 0; ni < 4; ++ni)
          acc[mi][ni] = MFMA16(af[mi], bf[ni], acc[mi][ni]);
    }
    // ds_reads retired before other waves may overwrite this buffer
    asm volatile("s_waitcnt lgkmcnt(0)" ::: "memory");
    __builtin_amdgcn_s_barrier();  // no vmem drain: prefetch stays in flight
    if (kt + 2 < nK) stage(cur, (kt + 2) << 6);  // refill the freed buffer
    cur ^= 1;
  }
  if (mode == 0) {
#pragma unroll
    for (int ni = 0; ni < 4; ++ni) {
      int col = n0 + wn + ni * 16 + lr;
      int s = col / 768;
      int hh = (col - s * 768) >> 6;
      int d = col & 63;
      if (s == 2) {
#pragma unroll
        for (int mi = 0; mi < MI; ++mi) {
          int row0 = m0 + wm + mi * 16 + lc * 4;
          int b = row0 >> 11, t = row0 & 2047;
          f16x4 tv;
#pragma unroll
          for (int r = 0; r < 4; ++r) tv[r] = (f16)acc[mi][ni][r];
          // 4 consecutive t = 4 consecutive e within one fragment octet
          *(f16x4*)&Vt[((size_t)(b * 12 + hh) << 17) | v_idx(t, d)] = tv;
        }
      } else {
        f16* dst = (s == 0) ? Qo : Ko;
#pragma unroll
        for (int mi = 0; mi < MI; ++mi)
#pragma unroll
          for (int r = 0; r < 4; ++r) {
            int row = m0 + wm + mi * 16 + lc * 4 + r;
            int b = row >> 11, t = row & 2047;
            dst[((size_t)(b * 12 + hh) << 17) | kq_idx(t, d)] =
                (f16)acc[mi][ni][r];
          }
      }
    }
  } else {
#pragma unroll
    for (int ni = 0; ni < 4; ++ni) {
      int col = n0 + wn + ni * 16 + lr;
      float bv = bias[col];
#pragma unroll
      for (int mi = 0; mi < MI; ++mi)
#pragma unroll
        for (int r = 0; r < 4; ++r) {
          int row = m0 + wm + mi * 16 + lc * 4 + r;
          out[(size_t)row * 768 + col] = acc[mi][ni][r] + bv;
        }
    }
  }
}

// ---- causal softplus-normalized attention: 4-wave split-K, P in registers ----
// Block (bh, qt), 256 threads. Wave wv handles 64-key tiles kt = wv, wv+4, ...
// Q/K/V live in FRAGMENT-layout buffers -> every load is base + lane*16B,
// fully coalesced (1 KB/instr, 8 cache lines instead of 32 — the r13 fix).
// Swapped 32x32 MFMA body: S = mfma32(A=K, B=Q); softplus+rowsum in-lane;
// P->f16 via cvt_pkrtz + permlane32_swap; O^T += mfma32(A=V-frag, B=P).
// K prefetched right after QK^T; all 8 V frags issued up-front (MLP).
// LDS untouched in the k-loop; single combine at the end (comb[4][32][68]).
// launch_bounds (256,3): bound 4 forces 64 arch-VGPRs -> catastrophic spills
// (r12, r18: FETCH 95-120MB, +50us). This body NEEDS ~110 regs; 3 is the max.
__global__ __launch_bounds__(256, 3) void k_attn(const f16* __restrict__ Q,
                                                 const f16* __restrict__ K,
                                                 const f16* __restrict__ Vt,
                                                 f16* __restrict__ Ab) {
  __shared__ __align__(16) char smem[35328];
  float (*comb)[32][68] = (float(*)[32][68])smem;  // [wv][q][d]
  float* rscomb = (float*)(smem + 34816);          // [wv][q]
  int tid = threadIdx.x, wv = tid >> 6, lane = tid & 63;
  int ql = lane & 31;
  int hi = lane >> 5;
  int hi4 = hi << 2;
  int bh = blockIdx.x;
  int qt = 63 - (int)blockIdx.y;  // heavy blocks dispatch first
  int qw = qt * 32;
  int b = bh / 12, h = bh - b * 12;
  const f16* Qp = Q + ((size_t)bh << 17);
  const f16* Kp = K + ((size_t)bh << 17);
  const f16* Vp = Vt + ((size_t)bh << 17);
  int l8 = lane * 8;

  const f16 a16 = (f16)0.18033688f;  // 0.125 * log2(e): fold scale into Q
  f16x8 qf[4];
#pragma unroll
  for (int c = 0; c < 4; ++c) {
    qf[c] = *(const f16x8*)&Qp[((qw >> 5) * 4 + c) * 512 + l8];
    qf[c] *= a16;
  }

  f32x16 o0 = {}, o1 = {};  // O^T[d = db*32 + crow(r,hi)][q] partials
  float rsp[4] = {0.f, 0.f, 0.f, 0.f};
  f16x8 kf[2][4];

  auto loadK = [&](int kb) {
#pragma unroll
    for (int kblk = 0; kblk < 2; ++kblk)
#pragma unroll
      for (int c = 0; c < 4; ++c)
        kf[kblk][c] =
            *(const f16x8*)&Kp[(((kb >> 5) + kblk) * 4 + c) * 512 + l8];
  };
  auto vfrag = [&](int kb32, int db, int ks) {
    return *(const f16x8*)&Vp[((kb32 * 2 + db) * 2 + ks) * 512 + l8];
  };

  // softplus: w' = log2(1+2^z) (uniform ln2 cancels in w/rowsum), in-place.
  auto spblk = [&](f32x16& sv, bool domask) {
#pragma unroll
    for (int r = 0; r < 16; ++r) {
      float z = sv[r];
      float w = __builtin_amdgcn_logf(1.f + __builtin_amdgcn_exp2f(z));
      if (domask) {
        int kl = (r & 3) + ((r >> 2) << 3) + hi4;
        w = (kl <= ql) ? w : 0.f;
      }
      rsp[r & 3] += w;
      sv[r] = w;
    }
  };

  // pack P to f16, exchange halves, feed PV for one 32-key block
  auto pvblk = [&](f32x16& sv, f16x8& vfa, f16x8& vfa2, f16x8& vfb,
                   f16x8& vfb2) {
#pragma unroll
    for (int ks = 0; ks < 2; ++ks) {
      unsigned Aw = pkrtz(sv[ks * 8 + 0], sv[ks * 8 + 1]);
      unsigned Bw = pkrtz(sv[ks * 8 + 2], sv[ks * 8 + 3]);
      unsigned Cw = pkrtz(sv[ks * 8 + 4], sv[ks * 8 + 5]);
      unsigned Dw = pkrtz(sv[ks * 8 + 6], sv[ks * 8 + 7]);
      xch(Aw, Cw);
      xch(Bw, Dw);
      union { unsigned u[4]; f16x8 v; } pf;
      pf.u[0] = Aw; pf.u[1] = Bw; pf.u[2] = Cw; pf.u[3] = Dw;
      o0 = MFMA32(ks ? vfa2 : vfa, pf.v, o0);
      o1 = MFMA32(ks ? vfb2 : vfb, pf.v, o1);
    }
  };

  auto tile = [&](int kb, bool dob1, bool mask, int kbn) {
    // 1. QK^T on prefetched kf (kf dead after this)
    f32x16 s0 = {}, s1 = {};
#pragma unroll
    for (int c = 0; c < 4; ++c) s0 = MFMA32(kf[0][c], qf[c], s0);
    if (dob1) {
#pragma unroll
      for (int c = 0; c < 4; ++c) s1 = MFMA32(kf[1][c], qf[c], s1);
    }
    // 2. prefetch this wave's next K immediately (longest latency to hide)
    if (kbn >= 0) loadK(kbn);
    // 3. all 8 V fragments issued up-front (coalesced; MLP)
    int kb32 = kb >> 5;
    f16x8 va0 = vfrag(kb32, 0, 0), va1 = vfrag(kb32, 0, 1);
    f16x8 vb0 = vfrag(kb32, 1, 0), vb1 = vfrag(kb32, 1, 1);
    f16x8 wa0, wa1, wb0, wb1;
    if (dob1) {
      wa0 = vfrag(kb32 + 1, 0, 0); wa1 = vfrag(kb32 + 1, 0, 1);
      wb0 = vfrag(kb32 + 1, 1, 0); wb1 = vfrag(kb32 + 1, 1, 1);
    }
    // 4. softplus + pack + PV per 32-key block
    spblk(s0, mask && !dob1);
    pvblk(s0, va0, va1, vb0, vb1);
    if (dob1) {
      spblk(s1, mask);
      pvblk(s1, wa0, wa1, wb0, wb1);
    }
  };

  int dt = qt >> 1;     // diagonal 64-tile index
  bool odd = (qt & 1);  // odd: kblk0 full, kblk1 diag; even: kblk0 diag only
  int nfull = (dt > wv) ? ((dt - wv + 3) >> 2) : 0;  // full tiles for this wave
  bool owndiag = ((dt & 3) == wv);
  if (nfull > 0 || owndiag) loadK(nfull > 0 ? wv * 64 : dt * 64);
  for (int i = 0; i < nfull; ++i) {
    int kb = (wv + 4 * i) * 64;
    int kbn = (i + 1 < nfull) ? kb + 256 : (owndiag ? dt * 64 : -1);
    tile(kb, true, false, kbn);
  }
  if (owndiag) tile(dt * 64, odd, true, -1);

  // per-wave rowsum for q=ql (combine the two key-halves)
  float rs = (rsp[0] + rsp[1]) + (rsp[2] + rsp[3]);
  rs += __shfl_xor(rs, 32);

  // deposit per-wave partials (LDS first touched here; no prior barrier needed)
  if (hi == 0) rscomb[wv * 32 + ql] = rs;
#pragma unroll
  for (int db = 0; db < 2; ++db) {
    const f32x16& oo = db ? o1 : o0;
#pragma unroll
    for (int r = 0; r < 16; ++r) {
      int d = db * 32 + (r & 3) + ((r >> 2) << 3) + hi4;
      comb[wv][ql][d] = oo[r];
    }
  }
  __syncthreads();

  // cross-wave combine: thread -> (row, 8 d's); normalize; store f16
  int row = tid >> 3, d0 = (tid & 7) << 3;
  float inv = 1.0f / (rscomb[row] + rscomb[32 + row] + rscomb[64 + row] +
                      rscomb[96 + row]);
  float sum[8] = {};
#pragma unroll
  for (int w = 0; w < 4; ++w) {
    float4 a = *(const float4*)&comb[w][row][d0];
    float4 c = *(const float4*)&comb[w][row][d0 + 4];
    sum[0] += a.x; sum[1] += a.y; sum[2] += a.z; sum[3] += a.w;
    sum[4] += c.x; sum[5] += c.y; sum[6] += c.z; sum[7] += c.w;
  }
  f16x8 o8;
#pragma unroll
  for (int e = 0; e < 8; ++e) o8[e] = (f16)(sum[e] * inv);
  *(f16x8*)&Ab[((size_t)b * 2048 + qw + row) * 768 + h * 64 + d0] = o8;
}

// ---------------- host ----------------
extern "C" void kernel_launch(void* const* d_in, const int* in_sizes, int n_in,
                              void* d_out, int out_size, void* d_ws,
                              size_t ws_size, hipStream_t stream) {
  const float* x = (const float*)d_in[0];
  const float* Wqkv = (const float*)d_in[1];
  const float* Wproj = (const float*)d_in[2];
  const float* bproj = (const float*)d_in[3];
  float* out = (float*)d_out;
  char* ws = (char*)d_ws;

  f16* xb     = (f16*)(ws + 0);         // 4096x768
  f16* WqkvT  = (f16*)(ws + 6291456);   // 2304x768
  f16* WprojT = (f16*)(ws + 9830400);   // 768x768
  f16* Qb     = (f16*)(ws + 11010048);  // 24x131072 (fragment layout)
  f16* Kb     = (f16*)(ws + 17301504);  // 24x131072 (fragment layout)
  f16* Vtb    = (f16*)(ws + 23592960);  // 24x131072 (fragment layout)
  f16* Ab     = (f16*)(ws + 29884416);  // 4096x768
  // total 36,175,872 B

  k_prep<<<1344, 256, 0, stream>>>(x, xb, Wqkv, WqkvT, Wproj, WprojT);
  k_gemm<64><<<dim3(64, 18), 256, 0, stream>>>(xb, WqkvT, 4096, 2304, 768, 0,
                                               Qb, Kb, Vtb, nullptr, nullptr);
  k_attn<<<dim3(24, 64), 256, 0, stream>>>(Qb, Kb, Vtb, Ab);
  k_gemm<64><<<dim3(64, 6), 256, 0, stream>>>(Ab, WprojT, 4096, 768, 768, 1,
                                              nullptr, nullptr, nullptr, bproj,
                                              out);
}